// Round 10
// baseline (277.550 us; speedup 1.0000x reference)
//
#include <hip/hip_runtime.h>
#include <hip/hip_bf16.h>

// Block_4776003633552: transformer block, B=4 T=2048 C=512 H=8 D=64. fp32 I/O.
// Reference quirks: scale = C^-0.5; softmax over QUERY axis (axis=-2) =>
//   out_t = sum_{s<=t} exp(sc*q_t.k_s) * v_s / L_s,  L_s = sum_{t>=s} exp(sc*q_t.k_s).
// Round 10: attention strips halved to 64 rows, pairs {i,31-i} -> 512 blocks =
// 2 blocks/CU co-residency (attnout LDS 71KB, colsum 29KB). Independent blocks
// overlap each other's exp->P->PV dependency chains (round-6/9 lesson: intra-
// block waves don't decouple; separate blocks do). GEMMs unchanged.

typedef __hip_bfloat16 bf16;
typedef __bf16 b8v __attribute__((ext_vector_type(8)));   // MFMA A/B fragment (8 bf16)
typedef float  f32x4 __attribute__((ext_vector_type(4))); // MFMA C/D fragment
typedef short  s8v  __attribute__((ext_vector_type(8)));  // 16B bf16 copy chunk
typedef short  s4v  __attribute__((ext_vector_type(4)));  // 8B packed chunk

#define B_   4
#define T_   2048
#define C_   512
#define H_   8
#define D_   64
#define BT_  (B_ * T_)
#define C4_  (4 * C_)
#define EPS_ 1e-5f
#define SCALE_ 0.04419417382415922f  // 1/sqrt(512)

#define MFMA16(a, b, c) __builtin_amdgcn_mfma_f32_16x16x32_bf16(a, b, c, 0, 0, 0)

static __device__ __forceinline__ float b2f(bf16 x) { return __bfloat162float(x); }
static __device__ __forceinline__ bf16  f2b(float x) { return __float2bfloat16(x); }
static __device__ __forceinline__ float s2f(short x) {
    return b2f(__builtin_bit_cast(bf16, x));
}
// packed 2xfp32 -> 2xbf16 (v_cvt_pk_bf16_f32); memcpy because __hip_bfloat162
// is not trivially copyable (bit_cast rejected).
static __device__ __forceinline__ unsigned int pk2(float a, float b) {
    float2 f;
    f.x = a;
    f.y = b;
    __hip_bfloat162 h = __float22bfloat162_rn(f);
    unsigned int u;
    __builtin_memcpy(&u, &h, 4);
    return u;
}

// ---------------- LayerNorm over C=512, one block per row ----------------
static __device__ __forceinline__ float ldv(const float* p) { return *p; }
static __device__ __forceinline__ float ldv(const bf16* p)  { return b2f(*p); }

template <typename TIN>
__global__ __launch_bounds__(256) void ln_kernel(const TIN* __restrict__ x,
                                                 const float* __restrict__ g,
                                                 const float* __restrict__ be,
                                                 bf16* __restrict__ out) {
    const int row = blockIdx.x;
    const int tid = threadIdx.x;
    const TIN* xr = x + (size_t)row * C_;
    float v0 = ldv(xr + tid * 2);
    float v1 = ldv(xr + tid * 2 + 1);
    float s = v0 + v1;
    float sq = v0 * v0 + v1 * v1;
    #pragma unroll
    for (int o = 32; o > 0; o >>= 1) {
        s += __shfl_down(s, o);
        sq += __shfl_down(sq, o);
    }
    __shared__ float ws[8], wsq[8];
    const int wid = tid >> 6, lane = tid & 63;
    if (lane == 0) { ws[wid] = s; wsq[wid] = sq; }
    __syncthreads();
    if (tid == 0) {
        float ts = 0.f, tq = 0.f;
        #pragma unroll
        for (int i = 0; i < 4; i++) { ts += ws[i]; tq += wsq[i]; }
        float mu = ts * (1.f / C_);
        float var = tq * (1.f / C_) - mu * mu;
        ws[4] = mu;
        wsq[4] = rsqrtf(var + EPS_);
    }
    __syncthreads();
    const float mu = ws[4], rstd = wsq[4];
    bf16* orow = out + (size_t)row * C_;
    orow[tid * 2]     = f2b((v0 - mu) * rstd * g[tid * 2]     + be[tid * 2]);
    orow[tid * 2 + 1] = f2b((v1 - mu) * rstd * g[tid * 2 + 1] + be[tid * 2 + 1]);
}

// ---------------- All weight transposes in one launch (768 blocks) ----------------
__global__ __launch_bounds__(256) void transpose_all(const float* __restrict__ Wq,
                                                     const float* __restrict__ Wk,
                                                     const float* __restrict__ Wv,
                                                     const float* __restrict__ Wo,
                                                     const float* __restrict__ W1,
                                                     const float* __restrict__ W2,
                                                     bf16* __restrict__ WqkvT,
                                                     bf16* __restrict__ WoT,
                                                     bf16* __restrict__ W1T,
                                                     bf16* __restrict__ W2T) {
    __shared__ float Ts[64][65];
    const int tid = threadIdx.x;
    const int id = blockIdx.x;
    if (id < 192) {
        const int sub = id / 64, rem = id % 64;
        const int x = rem & 7, hh = rem >> 3;
        const float* src = (sub == 0 ? Wq : sub == 1 ? Wk : Wv) + (size_t)hh * C_ * D_;
        bf16* dst = WqkvT + (size_t)sub * 512 * C_;
        const int c0 = x * 64;
        #pragma unroll
        for (int p = 0; p < 16; p++) {
            int idx = p * 256 + tid, i = idx >> 6, j = idx & 63;
            Ts[i][j] = src[(size_t)(c0 + i) * D_ + j];
        }
        __syncthreads();
        #pragma unroll
        for (int p = 0; p < 16; p++) {
            int idx = p * 256 + tid, j = idx >> 6, i = idx & 63;
            dst[(size_t)(hh * 64 + j) * C_ + c0 + i] = f2b(Ts[i][j]);
        }
    } else {
        const float* src;
        bf16* dst;
        int r0, c0, R, Cc;
        if (id < 256) {
            int rem = id - 192;
            src = Wo; dst = WoT; R = 512; Cc = 512;
            r0 = (rem & 7) * 64; c0 = (rem >> 3) * 64;
        } else if (id < 512) {
            int rem = id - 256;
            src = W1; dst = W1T; R = 512; Cc = 2048;
            r0 = (rem & 7) * 64; c0 = (rem >> 3) * 64;
        } else {
            int rem = id - 512;
            src = W2; dst = W2T; R = 2048; Cc = 512;
            r0 = (rem & 31) * 64; c0 = (rem >> 5) * 64;
        }
        #pragma unroll
        for (int p = 0; p < 16; p++) {
            int idx = p * 256 + tid, i = idx >> 6, j = idx & 63;
            Ts[i][j] = src[(size_t)(r0 + i) * Cc + c0 + j];
        }
        __syncthreads();
        #pragma unroll
        for (int p = 0; p < 16; p++) {
            int idx = p * 256 + tid, j = idx >> 6, i = idx & 63;
            dst[(size_t)(c0 + j) * R + r0 + i] = f2b(Ts[i][j]);
        }
    }
}

// ---------------- MFMA GEMM (256 thr): C[M,N] = A[M,K] @ Bt[N,K]^T ----------------
// MODE 1: +bias +relu -> bf16.  MODE 4: QKV split (q,k -> qkvb; v -> vt).
template <int MODE>
__global__ __launch_bounds__(256) void mfma_gemm(const bf16* __restrict__ A,
                                                 const bf16* __restrict__ Bt,
                                                 const float* __restrict__ bias,
                                                 bf16* __restrict__ outb,
                                                 bf16* __restrict__ qkvb,
                                                 bf16* __restrict__ vt,
                                                 int M, int N, int K) {
    __shared__ short As[128 * 32];
    __shared__ short Bs[128 * 32];
    const int tid = threadIdx.x;
    const int lane = tid & 63, wv = tid >> 6;
    const int wm = wv >> 1, wn = wv & 1;
    const int m0 = blockIdx.x * 128, n0 = blockIdx.y * 128;
    const int lrow = lane >> 2, lk = (lane & 3) * 8;
    const int lm = lane & 15, quad = lane >> 4;

    f32x4 acc[4][4];
    #pragma unroll
    for (int r = 0; r < 4; r++)
        #pragma unroll
        for (int c = 0; c < 4; c++) {
            f32x4 z = {0.f, 0.f, 0.f, 0.f};
            acc[r][c] = z;
        }

    for (int k0 = 0; k0 < K; k0 += 32) {
        #pragma unroll
        for (int cc = 0; cc < 2; cc++) {
            const int row = cc * 64 + wv * 16 + lrow;
            const bf16* ga = A + (size_t)(m0 + row) * K + k0 + lk;
            __builtin_amdgcn_global_load_lds(
                (const __attribute__((address_space(1))) void*)ga,
                (__attribute__((address_space(3))) void*)&As[(cc * 64 + wv * 16) * 32],
                16, 0, 0);
            const bf16* gb = Bt + (size_t)(n0 + row) * K + k0 + lk;
            __builtin_amdgcn_global_load_lds(
                (const __attribute__((address_space(1))) void*)gb,
                (__attribute__((address_space(3))) void*)&Bs[(cc * 64 + wv * 16) * 32],
                16, 0, 0);
        }
        __syncthreads();
        b8v af[4], bfr[4];
        #pragma unroll
        for (int r = 0; r < 4; r++)
            af[r] = *(const b8v*)&As[(wm * 64 + r * 16 + lm) * 32 + quad * 8];
        #pragma unroll
        for (int c = 0; c < 4; c++)
            bfr[c] = *(const b8v*)&Bs[(wn * 64 + c * 16 + lm) * 32 + quad * 8];
        #pragma unroll
        for (int r = 0; r < 4; r++)
            #pragma unroll
            for (int c = 0; c < 4; c++)
                acc[r][c] = MFMA16(af[r], bfr[c], acc[r][c]);
        __syncthreads();
    }

    #pragma unroll
    for (int r = 0; r < 4; r++) {
        const int mbase = m0 + wm * 64 + r * 16 + quad * 4;
        #pragma unroll
        for (int c = 0; c < 4; c++) {
            const int n = n0 + wn * 64 + c * 16 + lm;
            #pragma unroll
            for (int reg = 0; reg < 4; reg++) {
                const int m = mbase + reg;
                float v = acc[r][c][reg];
                if (MODE == 1) {
                    v += bias[n];
                    v = fmaxf(v, 0.f);
                    outb[(size_t)m * N + n] = f2b(v);
                } else {  // MODE 4: QKV
                    if (n < 1024) {
                        qkvb[(size_t)m * 1024 + n] = f2b(v);
                    } else {
                        vt[((size_t)(m >> 11) * 512 + (n - 1024)) * T_ + (m & (T_ - 1))] =
                            f2b(v);
                    }
                }
            }
        }
    }
}

// ---------------- Split-K MFMA GEMM: partial[z] = A[:, zKh:(z+1)Kh] @ Bt^T ----------------
__global__ __launch_bounds__(256) void mfma_gemm_sk(const bf16* __restrict__ A,
                                                    const bf16* __restrict__ Bt,
                                                    bf16* __restrict__ part,
                                                    int M, int N, int K, int Khalf) {
    __shared__ short As[128 * 32];
    __shared__ short Bs[128 * 32];
    const int tid = threadIdx.x;
    const int lane = tid & 63, wv = tid >> 6;
    const int wm = wv >> 1, wn = wv & 1;
    const int m0 = blockIdx.x * 128, n0 = blockIdx.y * 128;
    const int kbase = blockIdx.z * Khalf;
    const int lrow = lane >> 2, lk = (lane & 3) * 8;
    const int lm = lane & 15, quad = lane >> 4;

    f32x4 acc[4][4];
    #pragma unroll
    for (int r = 0; r < 4; r++)
        #pragma unroll
        for (int c = 0; c < 4; c++) {
            f32x4 z = {0.f, 0.f, 0.f, 0.f};
            acc[r][c] = z;
        }

    for (int kk = 0; kk < Khalf; kk += 32) {
        const int k0 = kbase + kk;
        #pragma unroll
        for (int cc = 0; cc < 2; cc++) {
            const int row = cc * 64 + wv * 16 + lrow;
            const bf16* ga = A + (size_t)(m0 + row) * K + k0 + lk;
            __builtin_amdgcn_global_load_lds(
                (const __attribute__((address_space(1))) void*)ga,
                (__attribute__((address_space(3))) void*)&As[(cc * 64 + wv * 16) * 32],
                16, 0, 0);
            const bf16* gb = Bt + (size_t)(n0 + row) * K + k0 + lk;
            __builtin_amdgcn_global_load_lds(
                (const __attribute__((address_space(1))) void*)gb,
                (__attribute__((address_space(3))) void*)&Bs[(cc * 64 + wv * 16) * 32],
                16, 0, 0);
        }
        __syncthreads();
        b8v af[4], bfr[4];
        #pragma unroll
        for (int r = 0; r < 4; r++)
            af[r] = *(const b8v*)&As[(wm * 64 + r * 16 + lm) * 32 + quad * 8];
        #pragma unroll
        for (int c = 0; c < 4; c++)
            bfr[c] = *(const b8v*)&Bs[(wn * 64 + c * 16 + lm) * 32 + quad * 8];
        #pragma unroll
        for (int r = 0; r < 4; r++)
            #pragma unroll
            for (int c = 0; c < 4; c++)
                acc[r][c] = MFMA16(af[r], bfr[c], acc[r][c]);
        __syncthreads();
    }

    bf16* pz = part + (size_t)blockIdx.z * M * N;
    #pragma unroll
    for (int r = 0; r < 4; r++) {
        const int mbase = m0 + wm * 64 + r * 16 + quad * 4;
        #pragma unroll
        for (int c = 0; c < 4; c++) {
            const int n = n0 + wn * 64 + c * 16 + lm;
            #pragma unroll
            for (int reg = 0; reg < 4; reg++)
                pz[(size_t)(mbase + reg) * N + n] = f2b(acc[r][c][reg]);
        }
    }
}

// ---------------- reduce: out = p0 + p1 + bias + res (fp32 out) ----------------
__global__ __launch_bounds__(256) void reduce_w2(const bf16* __restrict__ part,
                                                 const float* __restrict__ bias,
                                                 const bf16* __restrict__ res,
                                                 float* __restrict__ out) {
    const size_t i = ((size_t)blockIdx.x * 256 + threadIdx.x) * 4;
    const int n = (int)(i & (C_ - 1));
    s4v a = *(const s4v*)(part + i);
    s4v b = *(const s4v*)(part + (size_t)BT_ * C_ + i);
    s4v rv = *(const s4v*)(res + i);
    float4 bs = *(const float4*)(bias + n);
    float4 o;
    o.x = s2f(a[0]) + s2f(b[0]) + bs.x + s2f(rv[0]);
    o.y = s2f(a[1]) + s2f(b[1]) + bs.y + s2f(rv[1]);
    o.z = s2f(a[2]) + s2f(b[2]) + bs.z + s2f(rv[2]);
    o.w = s2f(a[3]) + s2f(b[3]) + bs.w + s2f(rv[3]);
    *(float4*)(out + i) = o;
}

// ---------------- MFMA GEMM (512 thr): Wo (+bias +fp32 res -> bf16) ----------------
__global__ __launch_bounds__(512) void mfma_gemm2(const bf16* __restrict__ A,
                                                  const bf16* __restrict__ Bt,
                                                  const float* __restrict__ bias,
                                                  const float* __restrict__ resf,
                                                  bf16* __restrict__ outb,
                                                  int M, int N, int K) {
    __shared__ short As[128 * 32];
    __shared__ short Bs[128 * 32];
    const int tid = threadIdx.x;
    const int lane = tid & 63, wv = tid >> 6;       // 8 waves
    const int wm = wv >> 2, wn = wv & 3;            // 2 x 4
    const int m0 = blockIdx.x * 128, n0 = blockIdx.y * 128;
    const int lm = lane & 15, quad = lane >> 4;

    f32x4 acc[4][2];
    #pragma unroll
    for (int r = 0; r < 4; r++)
        #pragma unroll
        for (int c = 0; c < 2; c++) {
            f32x4 z = {0.f, 0.f, 0.f, 0.f};
            acc[r][c] = z;
        }

    for (int k0 = 0; k0 < K; k0 += 32) {
        const int row = wv * 16 + (lane >> 2);
        const int lk = (lane & 3) * 8;
        const bf16* ga = A + (size_t)(m0 + row) * K + k0 + lk;
        __builtin_amdgcn_global_load_lds(
            (const __attribute__((address_space(1))) void*)ga,
            (__attribute__((address_space(3))) void*)&As[(wv * 16) * 32],
            16, 0, 0);
        const bf16* gb = Bt + (size_t)(n0 + row) * K + k0 + lk;
        __builtin_amdgcn_global_load_lds(
            (const __attribute__((address_space(1))) void*)gb,
            (__attribute__((address_space(3))) void*)&Bs[(wv * 16) * 32],
            16, 0, 0);
        __syncthreads();
        b8v af[4], bfr[2];
        #pragma unroll
        for (int r = 0; r < 4; r++)
            af[r] = *(const b8v*)&As[(wm * 64 + r * 16 + lm) * 32 + quad * 8];
        #pragma unroll
        for (int c = 0; c < 2; c++)
            bfr[c] = *(const b8v*)&Bs[(wn * 32 + c * 16 + lm) * 32 + quad * 8];
        #pragma unroll
        for (int r = 0; r < 4; r++)
            #pragma unroll
            for (int c = 0; c < 2; c++)
                acc[r][c] = MFMA16(af[r], bfr[c], acc[r][c]);
        __syncthreads();
    }

    #pragma unroll
    for (int r = 0; r < 4; r++) {
        const int mbase = m0 + wm * 64 + r * 16 + quad * 4;
        #pragma unroll
        for (int c = 0; c < 2; c++) {
            const int n = n0 + wn * 32 + c * 16 + lm;
            #pragma unroll
            for (int reg = 0; reg < 4; reg++) {
                const int m = mbase + reg;
                float v = acc[r][c][reg] + bias[n] + resf[(size_t)m * N + n];
                outb[(size_t)m * N + n] = f2b(v);
            }
        }
    }
}

// ---------------- Pass 1: Lr[s] = 1 / sum_{t>=s} exp(sc*q_t.k_s) ----------------
// 64-key strips, pairs {i,31-i} -> grid (32 bh, 16 pairs) = 512 blocks, 33 iters
// each. Waves 4(t)x2(s-half). K frags strip-resident in registers. LDS ~29KB.
__global__ __launch_bounds__(512) void colsum_mfma(const bf16* __restrict__ qkv,
                                                   float* __restrict__ Lr) {
    __shared__ short Ks[64 * 72];
    __shared__ short Qs[2][64 * 72];
    __shared__ float red[4][64];
    const int tid = threadIdx.x, lane = tid & 63, wv = tid >> 6;
    const int wq = wv >> 1, wk = wv & 1;
    const int lm = lane & 15, quad = lane >> 4;
    const int bh = blockIdx.x, bb = bh >> 3, hh = bh & 7;
    const bf16* qbase = qkv + (size_t)bb * T_ * 1024 + hh * 64;
    const bf16* kbase = qbase + 512;
    const int r_ = tid >> 3, ch = tid & 7;
    for (int half = 0; half < 2; half++) {
        const int strip = half ? 31 - (int)blockIdx.y : (int)blockIdx.y;
        const int s0 = strip * 64;
        // stage resident K (visible after iter-0 barrier)
        *(s8v*)&Ks[r_ * 72 + ch * 8] =
            *(const s8v*)(kbase + (size_t)(s0 + r_) * 1024 + ch * 8);
        // preload Q tile 0 (t0 = s0)
        s8v qr = *(const s8v*)(qbase + (size_t)(s0 + r_) * 1024 + ch * 8);
        b8v bk[2][2];  // strip-resident K fragments (s = wk*32 + c*16 + lm)
        float csum[2] = {};
        const int niter = 32 - strip;
        for (int it = 0; it < niter; it++) {
            const int buf = it & 1;
            *(s8v*)&Qs[buf][r_ * 72 + ch * 8] = qr;
            __syncthreads();
            if (it == 0) {
                #pragma unroll
                for (int c = 0; c < 2; c++)
                    #pragma unroll
                    for (int k = 0; k < 2; k++)
                        bk[c][k] = *(const b8v*)&Ks[(wk * 32 + c * 16 + lm) * 72 +
                                                    k * 32 + quad * 8];
            }
            if (it + 1 < niter) {
                const int t1 = s0 + (it + 1) * 64;
                qr = *(const s8v*)(qbase + (size_t)(t1 + r_) * 1024 + ch * 8);
            }
            const int t0 = s0 + it * 64;
            b8v aq[2];
            #pragma unroll
            for (int k = 0; k < 2; k++)
                aq[k] = *(const b8v*)&Qs[buf][(wq * 16 + lm) * 72 + k * 32 + quad * 8];
            if (it == 0) {  // diagonal: causal mask needed
                #pragma unroll
                for (int c = 0; c < 2; c++) {
                    f32x4 S = {0.f, 0.f, 0.f, 0.f};
                    S = MFMA16(aq[0], bk[c][0], S);
                    S = MFMA16(aq[1], bk[c][1], S);
                    const int s = s0 + wk * 32 + c * 16 + lm;
                    #pragma unroll
                    for (int reg = 0; reg < 4; reg++) {
                        int t = t0 + wq * 16 + quad * 4 + reg;
                        if (t >= s) csum[c] += __expf(S[reg] * SCALE_);
                    }
                }
            } else {  // strictly below diagonal: no mask
                #pragma unroll
                for (int c = 0; c < 2; c++) {
                    f32x4 S = {0.f, 0.f, 0.f, 0.f};
                    S = MFMA16(aq[0], bk[c][0], S);
                    S = MFMA16(aq[1], bk[c][1], S);
                    csum[c] += __expf(S[0] * SCALE_) + __expf(S[1] * SCALE_) +
                               __expf(S[2] * SCALE_) + __expf(S[3] * SCALE_);
                }
            }
        }
        __syncthreads();  // all Ks/Qs reads done before reduction & restage
        #pragma unroll
        for (int c = 0; c < 2; c++) {
            float v = csum[c];
            v += __shfl_xor(v, 16);
            v += __shfl_xor(v, 32);
            if (lane < 16) red[wq][wk * 32 + c * 16 + lane] = v;
        }
        __syncthreads();
        if (tid < 64) {
            float s = red[0][tid] + red[1][tid] + red[2][tid] + red[3][tid];
            Lr[(size_t)bh * T_ + s0 + tid] = 1.0f / s;
        }
        __syncthreads();
    }
}

// ---------------- Pass 2: out_t = sum_{s<=t} exp(sc*q_t.k_s) * (v_s * Lr_s) ----------------
// 64-query strips, pairs {i,31-i} -> 512 blocks, 33 iters each, LDS ~71KB ->
// 2 blocks/CU. Waves 4(t: 16 rows)x2(s-half). Q frags strip-resident in regs.
// O cross-wave (s-half) fp32 reduction once per strip.
__global__ __launch_bounds__(512) void attnout_mfma(const bf16* __restrict__ qkv,
                                                    const bf16* __restrict__ vt,
                                                    const float* __restrict__ Lr,
                                                    bf16* __restrict__ attn) {
    __shared__ short Qs[64 * 72];
    __shared__ short Ps[64 * 72];
    __shared__ short Ks[2][64 * 72];
    __shared__ short Vt[2][64 * 72];
    __shared__ float Ored[64 * 68];  // [d 64][t 64+4 pad] fp32 partial O
    const int tid = threadIdx.x, lane = tid & 63, wv = tid >> 6;
    const int wm = wv >> 1, wn = wv & 1;
    const int lm = lane & 15, quad = lane >> 4;
    const int bh = blockIdx.x, bb = bh >> 3, hh = bh & 7;
    const bf16* qbase = qkv + (size_t)bb * T_ * 1024 + hh * 64;
    const bf16* kbase = qbase + 512;
    const bf16* vtb = vt + ((size_t)bb * 512 + hh * 64) * T_;
    const float* Lrb = Lr + (size_t)bh * T_;
    const int r_ = tid >> 3, ch = tid & 7;
    for (int half = 0; half < 2; half++) {
        const int strip = half ? 31 - (int)blockIdx.y : (int)blockIdx.y;
        const int tb = strip * 64;
        // stage Q strip (visible after iter-0 barrier)
        *(s8v*)&Qs[r_ * 72 + ch * 8] =
            *(const s8v*)(qbase + (size_t)(tb + r_) * 1024 + ch * 8);
        // preload K/V/Lr tile 0
        s8v kreg = *(const s8v*)(kbase + (size_t)r_ * 1024 + ch * 8);
        s8v vreg = *(const s8v*)(vtb + (size_t)r_ * T_ + ch * 8);
        float4 lr0 = *(const float4*)(Lrb + ch * 8);
        float4 lr1 = *(const float4*)(Lrb + ch * 8 + 4);
        b8v bq[2];  // strip-resident Q fragments (t = wm*16 + lm)
        f32x4 o[4];
        #pragma unroll
        for (int c = 0; c < 4; c++) {
            f32x4 z = {0.f, 0.f, 0.f, 0.f};
            o[c] = z;
        }
        const int niter = strip + 1;
        for (int it = 0; it < niter; it++) {
            const int s0 = it * 64, buf = it & 1;
            // scale V by 1/L (packed cvt) and commit staged tile
            uint4 vs;
            vs.x = pk2(s2f(vreg[0]) * lr0.x, s2f(vreg[1]) * lr0.y);
            vs.y = pk2(s2f(vreg[2]) * lr0.z, s2f(vreg[3]) * lr0.w);
            vs.z = pk2(s2f(vreg[4]) * lr1.x, s2f(vreg[5]) * lr1.y);
            vs.w = pk2(s2f(vreg[6]) * lr1.z, s2f(vreg[7]) * lr1.w);
            *(s8v*)&Ks[buf][r_ * 72 + ch * 8] = kreg;
            *(uint4*)&Vt[buf][r_ * 72 + ch * 8] = vs;
            __syncthreads();
            if (it == 0) {
                #pragma unroll
                for (int k = 0; k < 2; k++)
                    bq[k] = *(const b8v*)&Qs[(wm * 16 + lm) * 72 + k * 32 + quad * 8];
            }
            if (it + 1 < niter) {
                const int s1 = s0 + 64;
                kreg = *(const s8v*)(kbase + (size_t)(s1 + r_) * 1024 + ch * 8);
                vreg = *(const s8v*)(vtb + (size_t)r_ * T_ + s1 + ch * 8);
                lr0 = *(const float4*)(Lrb + s1 + ch * 8);
                lr1 = *(const float4*)(Lrb + s1 + ch * 8 + 4);
            }
            // S^T = K . Q^T over this wave's s-half (wn*32, 32 keys)
            b8v ak[2][2];
            #pragma unroll
            for (int c = 0; c < 2; c++)
                #pragma unroll
                for (int k = 0; k < 2; k++)
                    ak[c][k] = *(const b8v*)&Ks[buf][(wn * 32 + c * 16 + lm) * 72 +
                                                     k * 32 + quad * 8];
            const bool masked = (it == niter - 1);  // s0 == tb diagonal tile
            const int t = tb + wm * 16 + lm;
            #pragma unroll
            for (int c = 0; c < 2; c++) {
                f32x4 S = {0.f, 0.f, 0.f, 0.f};
                S = MFMA16(ak[c][0], bq[0], S);
                S = MFMA16(ak[c][1], bq[1], S);
                float e[4];
                #pragma unroll
                for (int reg = 0; reg < 4; reg++) e[reg] = __expf(S[reg] * SCALE_);
                if (masked) {
                    #pragma unroll
                    for (int reg = 0; reg < 4; reg++) {
                        int s = s0 + wn * 32 + c * 16 + quad * 4 + reg;
                        if (t < s) e[reg] = 0.f;
                    }
                }
                uint2 u;
                u.x = pk2(e[0], e[1]);
                u.y = pk2(e[2], e[3]);
                *(uint2*)&Ps[(wm * 16 + lm) * 72 + wn * 32 + c * 16 + quad * 4] = u;
            }
            // PV over this wave's s-half: A = P (wave-local), B = Vt
            b8v ap = *(const b8v*)&Ps[(wm * 16 + lm) * 72 + wn * 32 + quad * 8];
            #pragma unroll
            for (int c = 0; c < 4; c++) {
                b8v bv = *(const b8v*)&Vt[buf][(c * 16 + lm) * 72 + wn * 32 + quad * 8];
                o[c] = MFMA16(ap, bv, o[c]);
            }
        }
        // cross-wave O reduction (s-halves) once per strip
        if (wn == 1) {
            #pragma unroll
            for (int c = 0; c < 4; c++)
                *(f32x4*)&Ored[(c * 16 + lm) * 68 + wm * 16 + quad * 4] = o[c];
        }
        __syncthreads();
        if (wn == 0) {
            #pragma unroll
            for (int c = 0; c < 4; c++) {
                f32x4 p = *(const f32x4*)&Ored[(c * 16 + lm) * 68 + wm * 16 + quad * 4];
                #pragma unroll
                for (int reg = 0; reg < 4; reg++)
                    attn[(size_t)(bb * T_ + tb + wm * 16 + quad * 4 + reg) * C_ +
                         hh * 64 + c * 16 + lm] = f2b(o[c][reg] + p[reg]);
            }
        }
        __syncthreads();  // protect Qs/Ks/Vt/Ored restage in next half
    }
}

extern "C" void kernel_launch(void* const* d_in, const int* in_sizes, int n_in,
                              void* d_out, int out_size, void* d_ws, size_t ws_size,
                              hipStream_t stream) {
    const float* x   = (const float*)d_in[0];
    const float* Wq  = (const float*)d_in[1];
    const float* Wk  = (const float*)d_in[2];
    const float* Wv  = (const float*)d_in[3];
    const float* Wo  = (const float*)d_in[4];
    const float* bo  = (const float*)d_in[5];
    const float* W1  = (const float*)d_in[6];
    const float* b1  = (const float*)d_in[7];
    const float* W2  = (const float*)d_in[8];
    const float* b2  = (const float*)d_in[9];
    const float* g1  = (const float*)d_in[10];
    const float* be1 = (const float*)d_in[11];
    const float* g2  = (const float*)d_in[12];
    const float* be2 = (const float*)d_in[13];
    float* out = (float*)d_out;

    // Workspace (~62 MB). Region A (32 MB) time-multiplexed:
    //   [qkvb 16MB | attn 8MB | hbuf 8MB] then reused whole as ff1 (32MB).
    // h2 (8MB) + vt (8MB) contiguous, dead by W2 time -> split-K partials.
    char* w = (char*)d_ws;
    auto alloc = [&](size_t bytes) -> void* {
        void* p = (void*)w;
        w += (bytes + 255) & ~(size_t)255;
        return p;
    };
    bf16* regionA = (bf16*)alloc((size_t)BT_ * 2048 * sizeof(bf16));  // 32MB
    bf16* qkvb = regionA;                                // [BT][1024] (q|k)
    bf16* attn = regionA + (size_t)BT_ * 1024;           // [BT][512]
    bf16* hbuf = regionA + (size_t)BT_ * 1536;           // [BT][512]
    bf16* ff1  = regionA;                                // [BT][2048]
    bf16* x1     = (bf16*)alloc((size_t)BT_ * C_ * sizeof(bf16));
    bf16* h2     = (bf16*)alloc((size_t)BT_ * C_ * sizeof(bf16));    // -> partial 0
    bf16* vt     = (bf16*)alloc((size_t)B_ * 512 * T_ * sizeof(bf16)); // -> partial 1
    bf16* WqkvT  = (bf16*)alloc((size_t)1536 * C_ * sizeof(bf16));
    bf16* WoT    = (bf16*)alloc((size_t)C_ * C_ * sizeof(bf16));
    bf16* W1T    = (bf16*)alloc((size_t)C4_ * C_ * sizeof(bf16));
    bf16* W2T    = (bf16*)alloc((size_t)C_ * C4_ * sizeof(bf16));
    float* Lr    = (float*)alloc((size_t)B_ * H_ * T_ * sizeof(float));
    bf16* partK  = h2;  // h2(8MB)+vt(8MB) contiguous = 16MB bf16 partials

    // All weight transposes (fp32 -> bf16 [N][K]) in one launch
    transpose_all<<<768, 256, 0, stream>>>(Wq, Wk, Wv, Wo, W1, W2,
                                           WqkvT, WoT, W1T, W2T);
    // 1. h = LN(x)
    ln_kernel<float><<<BT_, 256, 0, stream>>>(x, g1, be1, hbuf);
    // 2. QKV GEMM: [8192,1536,512]; q,k -> qkvb, v -> vt (transposed)
    mfma_gemm<4><<<dim3(BT_ / 128, 1536 / 128), 256, 0, stream>>>(
        hbuf, WqkvT, nullptr, nullptr, qkvb, vt, BT_, 1536, C_);
    // 3. column-sum reciprocals (XCD-swizzled, 512 blocks)
    colsum_mfma<<<dim3(B_ * H_, 16), 512, 0, stream>>>(qkvb, Lr);
    // 4. attention output (XCD-swizzled, 512 blocks = 2/CU)
    attnout_mfma<<<dim3(B_ * H_, 16), 512, 0, stream>>>(qkvb, vt, Lr, attn);
    // 5. x1 = x + attn @ Wo + bo
    mfma_gemm2<<<dim3(BT_ / 128, C_ / 128), 512, 0, stream>>>(
        attn, WoT, bo, x, x1, BT_, C_, C_);
    // 6. h2 = LN(x1)
    ln_kernel<bf16><<<BT_, 256, 0, stream>>>(x1, g2, be2, h2);
    // 7. ff1 = relu(h2 @ W1 + b1)
    mfma_gemm<1><<<dim3(BT_ / 128, C4_ / 128), 256, 0, stream>>>(
        h2, W1T, b1, ff1, nullptr, nullptr, BT_, C4_, C_);
    // 8a. W2 split-K: partials (512 blocks -> 2/CU)
    mfma_gemm_sk<<<dim3(BT_ / 128, C_ / 128, 2), 256, 0, stream>>>(
        ff1, W2T, partK, BT_, C_, C4_, C4_ / 2);
    // 8b. out = p0 + p1 + b2 + x1
    reduce_w2<<<(BT_ * C_) / (256 * 4), 256, 0, stream>>>(partK, b2, x1, out);
}

// Round 11
// 274.850 us; speedup vs baseline: 1.0098x; 1.0098x over previous
//
#include <hip/hip_runtime.h>
#include <hip/hip_bf16.h>

// Block_4776003633552: transformer block, B=4 T=2048 C=512 H=8 D=64. fp32 I/O.
// Reference quirks: scale = C^-0.5; softmax over QUERY axis (axis=-2) =>
//   out_t = sum_{s<=t} exp(sc*q_t.k_s) * v_s / L_s,  L_s = sum_{t>=s} exp(sc*q_t.k_s).
// Round 11: attnout = 128-query strips (round-9 staging economy) split by s-tile
// PARITY across two blocks (round-10 occupancy: 512 blocks, LDS 72KB via Ored
// aliased onto the dead K/V dbuf -> 2 blocks/CU). Partial O buffers (dead hbuf/
// h2) merged by a small add kernel. exp -> v_exp2 with log2e folded into scale.

typedef __hip_bfloat16 bf16;
typedef __bf16 b8v __attribute__((ext_vector_type(8)));   // MFMA A/B fragment (8 bf16)
typedef float  f32x4 __attribute__((ext_vector_type(4))); // MFMA C/D fragment
typedef short  s8v  __attribute__((ext_vector_type(8)));  // 16B bf16 copy chunk
typedef short  s4v  __attribute__((ext_vector_type(4)));  // 8B packed chunk

#define B_   4
#define T_   2048
#define C_   512
#define H_   8
#define D_   64
#define BT_  (B_ * T_)
#define C4_  (4 * C_)
#define EPS_ 1e-5f
#define SCALE2_ 0.06375872465908385f  // (1/sqrt(512)) * log2(e): exp(x*s)=2^(x*s*log2e)

#define MFMA16(a, b, c) __builtin_amdgcn_mfma_f32_16x16x32_bf16(a, b, c, 0, 0, 0)
#define EXP2F(x) __builtin_amdgcn_exp2f(x)

static __device__ __forceinline__ float b2f(bf16 x) { return __bfloat162float(x); }
static __device__ __forceinline__ bf16  f2b(float x) { return __float2bfloat16(x); }
static __device__ __forceinline__ short f2bs(float x) {
    bf16 h = f2b(x);
    return __builtin_bit_cast(short, h);
}
static __device__ __forceinline__ float s2f(short x) {
    return b2f(__builtin_bit_cast(bf16, x));
}
// packed 2xfp32 -> 2xbf16 (v_cvt_pk_bf16_f32); memcpy because __hip_bfloat162
// is not trivially copyable (bit_cast rejected).
static __device__ __forceinline__ unsigned int pk2(float a, float b) {
    float2 f;
    f.x = a;
    f.y = b;
    __hip_bfloat162 h = __float22bfloat162_rn(f);
    unsigned int u;
    __builtin_memcpy(&u, &h, 4);
    return u;
}

// ---------------- LayerNorm over C=512, one block per row ----------------
static __device__ __forceinline__ float ldv(const float* p) { return *p; }
static __device__ __forceinline__ float ldv(const bf16* p)  { return b2f(*p); }

template <typename TIN>
__global__ __launch_bounds__(256) void ln_kernel(const TIN* __restrict__ x,
                                                 const float* __restrict__ g,
                                                 const float* __restrict__ be,
                                                 bf16* __restrict__ out) {
    const int row = blockIdx.x;
    const int tid = threadIdx.x;
    const TIN* xr = x + (size_t)row * C_;
    float v0 = ldv(xr + tid * 2);
    float v1 = ldv(xr + tid * 2 + 1);
    float s = v0 + v1;
    float sq = v0 * v0 + v1 * v1;
    #pragma unroll
    for (int o = 32; o > 0; o >>= 1) {
        s += __shfl_down(s, o);
        sq += __shfl_down(sq, o);
    }
    __shared__ float ws[8], wsq[8];
    const int wid = tid >> 6, lane = tid & 63;
    if (lane == 0) { ws[wid] = s; wsq[wid] = sq; }
    __syncthreads();
    if (tid == 0) {
        float ts = 0.f, tq = 0.f;
        #pragma unroll
        for (int i = 0; i < 4; i++) { ts += ws[i]; tq += wsq[i]; }
        float mu = ts * (1.f / C_);
        float var = tq * (1.f / C_) - mu * mu;
        ws[4] = mu;
        wsq[4] = rsqrtf(var + EPS_);
    }
    __syncthreads();
    const float mu = ws[4], rstd = wsq[4];
    bf16* orow = out + (size_t)row * C_;
    orow[tid * 2]     = f2b((v0 - mu) * rstd * g[tid * 2]     + be[tid * 2]);
    orow[tid * 2 + 1] = f2b((v1 - mu) * rstd * g[tid * 2 + 1] + be[tid * 2 + 1]);
}

// ---------------- All weight transposes in one launch (768 blocks) ----------------
__global__ __launch_bounds__(256) void transpose_all(const float* __restrict__ Wq,
                                                     const float* __restrict__ Wk,
                                                     const float* __restrict__ Wv,
                                                     const float* __restrict__ Wo,
                                                     const float* __restrict__ W1,
                                                     const float* __restrict__ W2,
                                                     bf16* __restrict__ WqkvT,
                                                     bf16* __restrict__ WoT,
                                                     bf16* __restrict__ W1T,
                                                     bf16* __restrict__ W2T) {
    __shared__ float Ts[64][65];
    const int tid = threadIdx.x;
    const int id = blockIdx.x;
    if (id < 192) {
        const int sub = id / 64, rem = id % 64;
        const int x = rem & 7, hh = rem >> 3;
        const float* src = (sub == 0 ? Wq : sub == 1 ? Wk : Wv) + (size_t)hh * C_ * D_;
        bf16* dst = WqkvT + (size_t)sub * 512 * C_;
        const int c0 = x * 64;
        #pragma unroll
        for (int p = 0; p < 16; p++) {
            int idx = p * 256 + tid, i = idx >> 6, j = idx & 63;
            Ts[i][j] = src[(size_t)(c0 + i) * D_ + j];
        }
        __syncthreads();
        #pragma unroll
        for (int p = 0; p < 16; p++) {
            int idx = p * 256 + tid, j = idx >> 6, i = idx & 63;
            dst[(size_t)(hh * 64 + j) * C_ + c0 + i] = f2b(Ts[i][j]);
        }
    } else {
        const float* src;
        bf16* dst;
        int r0, c0, R, Cc;
        if (id < 256) {
            int rem = id - 192;
            src = Wo; dst = WoT; R = 512; Cc = 512;
            r0 = (rem & 7) * 64; c0 = (rem >> 3) * 64;
        } else if (id < 512) {
            int rem = id - 256;
            src = W1; dst = W1T; R = 512; Cc = 2048;
            r0 = (rem & 7) * 64; c0 = (rem >> 3) * 64;
        } else {
            int rem = id - 512;
            src = W2; dst = W2T; R = 2048; Cc = 512;
            r0 = (rem & 31) * 64; c0 = (rem >> 5) * 64;
        }
        #pragma unroll
        for (int p = 0; p < 16; p++) {
            int idx = p * 256 + tid, i = idx >> 6, j = idx & 63;
            Ts[i][j] = src[(size_t)(r0 + i) * Cc + c0 + j];
        }
        __syncthreads();
        #pragma unroll
        for (int p = 0; p < 16; p++) {
            int idx = p * 256 + tid, j = idx >> 6, i = idx & 63;
            dst[(size_t)(c0 + j) * R + r0 + i] = f2b(Ts[i][j]);
        }
    }
}

// ---------------- MFMA GEMM (256 thr): C[M,N] = A[M,K] @ Bt[N,K]^T ----------------
// MODE 1: +bias +relu -> bf16.  MODE 4: QKV split (q,k -> qkvb; v -> vt).
template <int MODE>
__global__ __launch_bounds__(256) void mfma_gemm(const bf16* __restrict__ A,
                                                 const bf16* __restrict__ Bt,
                                                 const float* __restrict__ bias,
                                                 bf16* __restrict__ outb,
                                                 bf16* __restrict__ qkvb,
                                                 bf16* __restrict__ vt,
                                                 int M, int N, int K) {
    __shared__ short As[128 * 32];
    __shared__ short Bs[128 * 32];
    const int tid = threadIdx.x;
    const int lane = tid & 63, wv = tid >> 6;
    const int wm = wv >> 1, wn = wv & 1;
    const int m0 = blockIdx.x * 128, n0 = blockIdx.y * 128;
    const int lrow = lane >> 2, lk = (lane & 3) * 8;
    const int lm = lane & 15, quad = lane >> 4;

    f32x4 acc[4][4];
    #pragma unroll
    for (int r = 0; r < 4; r++)
        #pragma unroll
        for (int c = 0; c < 4; c++) {
            f32x4 z = {0.f, 0.f, 0.f, 0.f};
            acc[r][c] = z;
        }

    for (int k0 = 0; k0 < K; k0 += 32) {
        #pragma unroll
        for (int cc = 0; cc < 2; cc++) {
            const int row = cc * 64 + wv * 16 + lrow;
            const bf16* ga = A + (size_t)(m0 + row) * K + k0 + lk;
            __builtin_amdgcn_global_load_lds(
                (const __attribute__((address_space(1))) void*)ga,
                (__attribute__((address_space(3))) void*)&As[(cc * 64 + wv * 16) * 32],
                16, 0, 0);
            const bf16* gb = Bt + (size_t)(n0 + row) * K + k0 + lk;
            __builtin_amdgcn_global_load_lds(
                (const __attribute__((address_space(1))) void*)gb,
                (__attribute__((address_space(3))) void*)&Bs[(cc * 64 + wv * 16) * 32],
                16, 0, 0);
        }
        __syncthreads();
        b8v af[4], bfr[4];
        #pragma unroll
        for (int r = 0; r < 4; r++)
            af[r] = *(const b8v*)&As[(wm * 64 + r * 16 + lm) * 32 + quad * 8];
        #pragma unroll
        for (int c = 0; c < 4; c++)
            bfr[c] = *(const b8v*)&Bs[(wn * 64 + c * 16 + lm) * 32 + quad * 8];
        #pragma unroll
        for (int r = 0; r < 4; r++)
            #pragma unroll
            for (int c = 0; c < 4; c++)
                acc[r][c] = MFMA16(af[r], bfr[c], acc[r][c]);
        __syncthreads();
    }

    #pragma unroll
    for (int r = 0; r < 4; r++) {
        const int mbase = m0 + wm * 64 + r * 16 + quad * 4;
        #pragma unroll
        for (int c = 0; c < 4; c++) {
            const int n = n0 + wn * 64 + c * 16 + lm;
            #pragma unroll
            for (int reg = 0; reg < 4; reg++) {
                const int m = mbase + reg;
                float v = acc[r][c][reg];
                if (MODE == 1) {
                    v += bias[n];
                    v = fmaxf(v, 0.f);
                    outb[(size_t)m * N + n] = f2b(v);
                } else {  // MODE 4: QKV
                    if (n < 1024) {
                        qkvb[(size_t)m * 1024 + n] = f2b(v);
                    } else {
                        vt[((size_t)(m >> 11) * 512 + (n - 1024)) * T_ + (m & (T_ - 1))] =
                            f2b(v);
                    }
                }
            }
        }
    }
}

// ---------------- Split-K MFMA GEMM: partial[z] = A[:, zKh:(z+1)Kh] @ Bt^T ----------------
__global__ __launch_bounds__(256) void mfma_gemm_sk(const bf16* __restrict__ A,
                                                    const bf16* __restrict__ Bt,
                                                    bf16* __restrict__ part,
                                                    int M, int N, int K, int Khalf) {
    __shared__ short As[128 * 32];
    __shared__ short Bs[128 * 32];
    const int tid = threadIdx.x;
    const int lane = tid & 63, wv = tid >> 6;
    const int wm = wv >> 1, wn = wv & 1;
    const int m0 = blockIdx.x * 128, n0 = blockIdx.y * 128;
    const int kbase = blockIdx.z * Khalf;
    const int lrow = lane >> 2, lk = (lane & 3) * 8;
    const int lm = lane & 15, quad = lane >> 4;

    f32x4 acc[4][4];
    #pragma unroll
    for (int r = 0; r < 4; r++)
        #pragma unroll
        for (int c = 0; c < 4; c++) {
            f32x4 z = {0.f, 0.f, 0.f, 0.f};
            acc[r][c] = z;
        }

    for (int kk = 0; kk < Khalf; kk += 32) {
        const int k0 = kbase + kk;
        #pragma unroll
        for (int cc = 0; cc < 2; cc++) {
            const int row = cc * 64 + wv * 16 + lrow;
            const bf16* ga = A + (size_t)(m0 + row) * K + k0 + lk;
            __builtin_amdgcn_global_load_lds(
                (const __attribute__((address_space(1))) void*)ga,
                (__attribute__((address_space(3))) void*)&As[(cc * 64 + wv * 16) * 32],
                16, 0, 0);
            const bf16* gb = Bt + (size_t)(n0 + row) * K + k0 + lk;
            __builtin_amdgcn_global_load_lds(
                (const __attribute__((address_space(1))) void*)gb,
                (__attribute__((address_space(3))) void*)&Bs[(cc * 64 + wv * 16) * 32],
                16, 0, 0);
        }
        __syncthreads();
        b8v af[4], bfr[4];
        #pragma unroll
        for (int r = 0; r < 4; r++)
            af[r] = *(const b8v*)&As[(wm * 64 + r * 16 + lm) * 32 + quad * 8];
        #pragma unroll
        for (int c = 0; c < 4; c++)
            bfr[c] = *(const b8v*)&Bs[(wn * 64 + c * 16 + lm) * 32 + quad * 8];
        #pragma unroll
        for (int r = 0; r < 4; r++)
            #pragma unroll
            for (int c = 0; c < 4; c++)
                acc[r][c] = MFMA16(af[r], bfr[c], acc[r][c]);
        __syncthreads();
    }

    bf16* pz = part + (size_t)blockIdx.z * M * N;
    #pragma unroll
    for (int r = 0; r < 4; r++) {
        const int mbase = m0 + wm * 64 + r * 16 + quad * 4;
        #pragma unroll
        for (int c = 0; c < 4; c++) {
            const int n = n0 + wn * 64 + c * 16 + lm;
            #pragma unroll
            for (int reg = 0; reg < 4; reg++)
                pz[(size_t)(mbase + reg) * N + n] = f2b(acc[r][c][reg]);
        }
    }
}

// ---------------- reduce: out = p0 + p1 + bias + res (fp32 out) ----------------
__global__ __launch_bounds__(256) void reduce_w2(const bf16* __restrict__ part,
                                                 const float* __restrict__ bias,
                                                 const bf16* __restrict__ res,
                                                 float* __restrict__ out) {
    const size_t i = ((size_t)blockIdx.x * 256 + threadIdx.x) * 4;
    const int n = (int)(i & (C_ - 1));
    s4v a = *(const s4v*)(part + i);
    s4v b = *(const s4v*)(part + (size_t)BT_ * C_ + i);
    s4v rv = *(const s4v*)(res + i);
    float4 bs = *(const float4*)(bias + n);
    float4 o;
    o.x = s2f(a[0]) + s2f(b[0]) + bs.x + s2f(rv[0]);
    o.y = s2f(a[1]) + s2f(b[1]) + bs.y + s2f(rv[1]);
    o.z = s2f(a[2]) + s2f(b[2]) + bs.z + s2f(rv[2]);
    o.w = s2f(a[3]) + s2f(b[3]) + bs.w + s2f(rv[3]);
    *(float4*)(out + i) = o;
}

// ---------------- reduce: attn = p0 + p1 (bf16) ----------------
__global__ __launch_bounds__(256) void reduce_attn(const bf16* __restrict__ p0,
                                                   const bf16* __restrict__ p1,
                                                   bf16* __restrict__ attn) {
    const size_t i = ((size_t)blockIdx.x * 256 + threadIdx.x) * 8;
    s8v a = *(const s8v*)(p0 + i);
    s8v b = *(const s8v*)(p1 + i);
    s8v o;
    #pragma unroll
    for (int j = 0; j < 8; j++) o[j] = f2bs(s2f(a[j]) + s2f(b[j]));
    *(s8v*)(attn + i) = o;
}

// ---------------- MFMA GEMM (512 thr): Wo (+bias +fp32 res -> bf16) ----------------
__global__ __launch_bounds__(512) void mfma_gemm2(const bf16* __restrict__ A,
                                                  const bf16* __restrict__ Bt,
                                                  const float* __restrict__ bias,
                                                  const float* __restrict__ resf,
                                                  bf16* __restrict__ outb,
                                                  int M, int N, int K) {
    __shared__ short As[128 * 32];
    __shared__ short Bs[128 * 32];
    const int tid = threadIdx.x;
    const int lane = tid & 63, wv = tid >> 6;       // 8 waves
    const int wm = wv >> 2, wn = wv & 3;            // 2 x 4
    const int m0 = blockIdx.x * 128, n0 = blockIdx.y * 128;
    const int lm = lane & 15, quad = lane >> 4;

    f32x4 acc[4][2];
    #pragma unroll
    for (int r = 0; r < 4; r++)
        #pragma unroll
        for (int c = 0; c < 2; c++) {
            f32x4 z = {0.f, 0.f, 0.f, 0.f};
            acc[r][c] = z;
        }

    for (int k0 = 0; k0 < K; k0 += 32) {
        const int row = wv * 16 + (lane >> 2);
        const int lk = (lane & 3) * 8;
        const bf16* ga = A + (size_t)(m0 + row) * K + k0 + lk;
        __builtin_amdgcn_global_load_lds(
            (const __attribute__((address_space(1))) void*)ga,
            (__attribute__((address_space(3))) void*)&As[(wv * 16) * 32],
            16, 0, 0);
        const bf16* gb = Bt + (size_t)(n0 + row) * K + k0 + lk;
        __builtin_amdgcn_global_load_lds(
            (const __attribute__((address_space(1))) void*)gb,
            (__attribute__((address_space(3))) void*)&Bs[(wv * 16) * 32],
            16, 0, 0);
        __syncthreads();
        b8v af[4], bfr[2];
        #pragma unroll
        for (int r = 0; r < 4; r++)
            af[r] = *(const b8v*)&As[(wm * 64 + r * 16 + lm) * 32 + quad * 8];
        #pragma unroll
        for (int c = 0; c < 2; c++)
            bfr[c] = *(const b8v*)&Bs[(wn * 32 + c * 16 + lm) * 32 + quad * 8];
        #pragma unroll
        for (int r = 0; r < 4; r++)
            #pragma unroll
            for (int c = 0; c < 2; c++)
                acc[r][c] = MFMA16(af[r], bfr[c], acc[r][c]);
        __syncthreads();
    }

    #pragma unroll
    for (int r = 0; r < 4; r++) {
        const int mbase = m0 + wm * 64 + r * 16 + quad * 4;
        #pragma unroll
        for (int c = 0; c < 2; c++) {
            const int n = n0 + wn * 32 + c * 16 + lm;
            #pragma unroll
            for (int reg = 0; reg < 4; reg++) {
                const int m = mbase + reg;
                float v = acc[r][c][reg] + bias[n] + resf[(size_t)m * N + n];
                outb[(size_t)m * N + n] = f2b(v);
            }
        }
    }
}

// ---------------- Pass 1: Lr[s] = 1 / sum_{t>=s} exp(sc*q_t.k_s) ----------------
// 64-key strips, pairs {i,31-i} -> grid (32 bh, 16 pairs) = 512 blocks, 33 iters
// each. Waves 4(t)x2(s-half). K frags strip-resident in registers. LDS ~29KB.
__global__ __launch_bounds__(512) void colsum_mfma(const bf16* __restrict__ qkv,
                                                   float* __restrict__ Lr) {
    __shared__ short Ks[64 * 72];
    __shared__ short Qs[2][64 * 72];
    __shared__ float red[4][64];
    const int tid = threadIdx.x, lane = tid & 63, wv = tid >> 6;
    const int wq = wv >> 1, wk = wv & 1;
    const int lm = lane & 15, quad = lane >> 4;
    const int bh = blockIdx.x, bb = bh >> 3, hh = bh & 7;
    const bf16* qbase = qkv + (size_t)bb * T_ * 1024 + hh * 64;
    const bf16* kbase = qbase + 512;
    const int r_ = tid >> 3, ch = tid & 7;
    for (int half = 0; half < 2; half++) {
        const int strip = half ? 31 - (int)blockIdx.y : (int)blockIdx.y;
        const int s0 = strip * 64;
        // stage resident K (visible after iter-0 barrier)
        *(s8v*)&Ks[r_ * 72 + ch * 8] =
            *(const s8v*)(kbase + (size_t)(s0 + r_) * 1024 + ch * 8);
        // preload Q tile 0 (t0 = s0)
        s8v qr = *(const s8v*)(qbase + (size_t)(s0 + r_) * 1024 + ch * 8);
        b8v bk[2][2];  // strip-resident K fragments (s = wk*32 + c*16 + lm)
        float csum[2] = {};
        const int niter = 32 - strip;
        for (int it = 0; it < niter; it++) {
            const int buf = it & 1;
            *(s8v*)&Qs[buf][r_ * 72 + ch * 8] = qr;
            __syncthreads();
            if (it == 0) {
                #pragma unroll
                for (int c = 0; c < 2; c++)
                    #pragma unroll
                    for (int k = 0; k < 2; k++)
                        bk[c][k] = *(const b8v*)&Ks[(wk * 32 + c * 16 + lm) * 72 +
                                                    k * 32 + quad * 8];
            }
            if (it + 1 < niter) {
                const int t1 = s0 + (it + 1) * 64;
                qr = *(const s8v*)(qbase + (size_t)(t1 + r_) * 1024 + ch * 8);
            }
            const int t0 = s0 + it * 64;
            b8v aq[2];
            #pragma unroll
            for (int k = 0; k < 2; k++)
                aq[k] = *(const b8v*)&Qs[buf][(wq * 16 + lm) * 72 + k * 32 + quad * 8];
            if (it == 0) {  // diagonal: causal mask needed
                #pragma unroll
                for (int c = 0; c < 2; c++) {
                    f32x4 S = {0.f, 0.f, 0.f, 0.f};
                    S = MFMA16(aq[0], bk[c][0], S);
                    S = MFMA16(aq[1], bk[c][1], S);
                    const int s = s0 + wk * 32 + c * 16 + lm;
                    #pragma unroll
                    for (int reg = 0; reg < 4; reg++) {
                        int t = t0 + wq * 16 + quad * 4 + reg;
                        if (t >= s) csum[c] += EXP2F(S[reg] * SCALE2_);
                    }
                }
            } else {  // strictly below diagonal: no mask
                #pragma unroll
                for (int c = 0; c < 2; c++) {
                    f32x4 S = {0.f, 0.f, 0.f, 0.f};
                    S = MFMA16(aq[0], bk[c][0], S);
                    S = MFMA16(aq[1], bk[c][1], S);
                    csum[c] += EXP2F(S[0] * SCALE2_) + EXP2F(S[1] * SCALE2_) +
                               EXP2F(S[2] * SCALE2_) + EXP2F(S[3] * SCALE2_);
                }
            }
        }
        __syncthreads();  // all Ks/Qs reads done before reduction & restage
        #pragma unroll
        for (int c = 0; c < 2; c++) {
            float v = csum[c];
            v += __shfl_xor(v, 16);
            v += __shfl_xor(v, 32);
            if (lane < 16) red[wq][wk * 32 + c * 16 + lane] = v;
        }
        __syncthreads();
        if (tid < 64) {
            float s = red[0][tid] + red[1][tid] + red[2][tid] + red[3][tid];
            Lr[(size_t)bh * T_ + s0 + tid] = 1.0f / s;
        }
        __syncthreads();
    }
}

// ---------------- Pass 2: out_t = sum_{s<=t} exp(sc*q_t.k_s) * (v_s * Lr_s) ----------------
// 128-query strips, pairs {p,15-p}; each block handles even OR odd 64-key tiles
// (parity) -> grid (32, 16) = 512 blocks, 17 iters each, staging volume = one
// stage per tile per strip (round-9 economy). LDS arena 72KB (Ored aliased onto
// dead K/V dbuf) -> 2 blocks/CU. Partial O -> p0/p1, merged by reduce_attn.
__global__ __launch_bounds__(512) void attnout_mfma(const bf16* __restrict__ qkv,
                                                    const bf16* __restrict__ vt,
                                                    const float* __restrict__ Lr,
                                                    bf16* __restrict__ pout0,
                                                    bf16* __restrict__ pout1) {
    __shared__ __align__(16) char arena[73728];
    short* const Qs = (short*)arena;                 // [128*72] 18432 B
    short* const Ps = (short*)(arena + 18432);       // [128*72] 18432 B
    short* const KV = (short*)(arena + 36864);       // Ks[2][64*72] Vt[2][64*72] 36864 B
    float* const Ored = (float*)(arena + 36864);     // [64*132] 33792 B (aliases KV)
    const int tid = threadIdx.x, lane = tid & 63, wv = tid >> 6;
    const int wm = wv >> 1, wn = wv & 1;
    const int lm = lane & 15, quad = lane >> 4;
    const int bh = blockIdx.x, bb = bh >> 3, hh = bh & 7;
    const int pairIdx = blockIdx.y >> 1, parity = blockIdx.y & 1;
    bf16* const outP = parity ? pout1 : pout0;
    const bf16* qbase = qkv + (size_t)bb * T_ * 1024 + hh * 64;
    const bf16* kbase = qbase + 512;
    const bf16* vtb = vt + ((size_t)bb * 512 + hh * 64) * T_;
    const float* Lrb = Lr + (size_t)bh * T_;
    const int r_ = tid >> 3, ch = tid & 7;
    for (int half = 0; half < 2; half++) {
        const int strip = half ? 15 - pairIdx : pairIdx;
        const int tb = strip * 128;
        // stage Q strip (visible after iter-0 barrier)
        #pragma unroll
        for (int cc = 0; cc < 2; cc++) {
            int idx = cc * 512 + tid, qr = idx >> 3, qc = idx & 7;
            *(s8v*)&Qs[qr * 72 + qc * 8] =
                *(const s8v*)(qbase + (size_t)(tb + qr) * 1024 + qc * 8);
        }
        // preload K/V/Lr for tile 0 (s0 = parity*64)
        int s0 = parity * 64;
        s8v kreg = *(const s8v*)(kbase + (size_t)(s0 + r_) * 1024 + ch * 8);
        s8v vreg = *(const s8v*)(vtb + (size_t)r_ * T_ + s0 + ch * 8);
        float4 lr0 = *(const float4*)(Lrb + s0 + ch * 8);
        float4 lr1 = *(const float4*)(Lrb + s0 + ch * 8 + 4);
        b8v bq[2][2];  // strip-resident Q fragments (t = wm*32 + r*16 + lm)
        f32x4 o[2][4];
        #pragma unroll
        for (int r = 0; r < 2; r++)
            #pragma unroll
            for (int c = 0; c < 4; c++) {
                f32x4 z = {0.f, 0.f, 0.f, 0.f};
                o[r][c] = z;
            }
        const int niter = strip + 1;
        for (int it = 0; it < niter; it++) {
            s0 = (parity + 2 * it) * 64;
            const int buf = it & 1;
            short* const Ksb = KV + buf * (64 * 72);
            short* const Vsb = KV + 2 * (64 * 72) + buf * (64 * 72);
            // scale V by 1/L (packed cvt) and commit staged tile
            uint4 vs;
            vs.x = pk2(s2f(vreg[0]) * lr0.x, s2f(vreg[1]) * lr0.y);
            vs.y = pk2(s2f(vreg[2]) * lr0.z, s2f(vreg[3]) * lr0.w);
            vs.z = pk2(s2f(vreg[4]) * lr1.x, s2f(vreg[5]) * lr1.y);
            vs.w = pk2(s2f(vreg[6]) * lr1.z, s2f(vreg[7]) * lr1.w);
            *(s8v*)&Ksb[r_ * 72 + ch * 8] = kreg;
            *(uint4*)&Vsb[r_ * 72 + ch * 8] = vs;
            __syncthreads();
            if (it == 0) {
                #pragma unroll
                for (int r = 0; r < 2; r++)
                    #pragma unroll
                    for (int k = 0; k < 2; k++)
                        bq[r][k] = *(const b8v*)&Qs[(wm * 32 + r * 16 + lm) * 72 +
                                                    k * 32 + quad * 8];
            }
            if (it + 1 < niter) {
                const int s1 = s0 + 128;
                kreg = *(const s8v*)(kbase + (size_t)(s1 + r_) * 1024 + ch * 8);
                vreg = *(const s8v*)(vtb + (size_t)r_ * T_ + s1 + ch * 8);
                lr0 = *(const float4*)(Lrb + s1 + ch * 8);
                lr1 = *(const float4*)(Lrb + s1 + ch * 8 + 4);
            }
            // S^T = K . Q^T over this wave's s-half (wn*32, 32 keys)
            b8v ak[2][2];
            #pragma unroll
            for (int c = 0; c < 2; c++)
                #pragma unroll
                for (int k = 0; k < 2; k++)
                    ak[c][k] = *(const b8v*)&Ksb[(wn * 32 + c * 16 + lm) * 72 +
                                                 k * 32 + quad * 8];
            const bool masked = (it == niter - 1);  // only the diagonal-region tile
            #pragma unroll
            for (int r = 0; r < 2; r++) {
                const int t = tb + wm * 32 + r * 16 + lm;
                #pragma unroll
                for (int c = 0; c < 2; c++) {
                    f32x4 S = {0.f, 0.f, 0.f, 0.f};
                    S = MFMA16(ak[c][0], bq[r][0], S);
                    S = MFMA16(ak[c][1], bq[r][1], S);
                    float e[4];
                    #pragma unroll
                    for (int reg = 0; reg < 4; reg++)
                        e[reg] = EXP2F(S[reg] * SCALE2_);
                    if (masked) {
                        #pragma unroll
                        for (int reg = 0; reg < 4; reg++) {
                            int s = s0 + wn * 32 + c * 16 + quad * 4 + reg;
                            if (t < s) e[reg] = 0.f;
                        }
                    }
                    uint2 u;
                    u.x = pk2(e[0], e[1]);
                    u.y = pk2(e[2], e[3]);
                    *(uint2*)&Ps[(wm * 32 + r * 16 + lm) * 72 + wn * 32 + c * 16 +
                                 quad * 4] = u;
                }
            }
            // PV over this wave's s-half: A = P (wave-local), B = V'
            #pragma unroll
            for (int r = 0; r < 2; r++) {
                b8v ap = *(const b8v*)&Ps[(wm * 32 + r * 16 + lm) * 72 + wn * 32 +
                                          quad * 8];
                #pragma unroll
                for (int c = 0; c < 4; c++) {
                    b8v bv = *(const b8v*)&Vsb[(c * 16 + lm) * 72 + wn * 32 + quad * 8];
                    o[r][c] = MFMA16(ap, bv, o[r][c]);
                }
            }
        }
        // cross-wave s-half reduction; Ored aliases the K/V dbuf -> barrier first
        __syncthreads();
        if (wn == 1) {
            #pragma unroll
            for (int r = 0; r < 2; r++)
                #pragma unroll
                for (int c = 0; c < 4; c++)
                    *(f32x4*)&Ored[(c * 16 + lm) * 132 + wm * 32 + r * 16 + quad * 4] =
                        o[r][c];
        }
        __syncthreads();
        if (wn == 0) {
            #pragma unroll
            for (int r = 0; r < 2; r++)
                #pragma unroll
                for (int c = 0; c < 4; c++) {
                    f32x4 p = *(const f32x4*)&Ored[(c * 16 + lm) * 132 + wm * 32 +
                                                   r * 16 + quad * 4];
                    #pragma unroll
                    for (int reg = 0; reg < 4; reg++)
                        outP[(size_t)(bb * T_ + tb + wm * 32 + r * 16 + quad * 4 +
                                      reg) * C_ + hh * 64 + c * 16 + lm] =
                            f2b(o[r][c][reg] + p[reg]);
                }
        }
        __syncthreads();  // protect Qs/KV/Ored restage in next half
    }
}

extern "C" void kernel_launch(void* const* d_in, const int* in_sizes, int n_in,
                              void* d_out, int out_size, void* d_ws, size_t ws_size,
                              hipStream_t stream) {
    const float* x   = (const float*)d_in[0];
    const float* Wq  = (const float*)d_in[1];
    const float* Wk  = (const float*)d_in[2];
    const float* Wv  = (const float*)d_in[3];
    const float* Wo  = (const float*)d_in[4];
    const float* bo  = (const float*)d_in[5];
    const float* W1  = (const float*)d_in[6];
    const float* b1  = (const float*)d_in[7];
    const float* W2  = (const float*)d_in[8];
    const float* b2  = (const float*)d_in[9];
    const float* g1  = (const float*)d_in[10];
    const float* be1 = (const float*)d_in[11];
    const float* g2  = (const float*)d_in[12];
    const float* be2 = (const float*)d_in[13];
    float* out = (float*)d_out;

    // Workspace (~62 MB). Region A (32 MB) time-multiplexed:
    //   [qkvb 16MB | attn 8MB | hbuf 8MB] then reused whole as ff1 (32MB).
    // hbuf dead after QKV -> attnout partial 0. h2 unused until step 6 ->
    // attnout partial 1. h2+vt (contiguous 16MB) dead by W2 -> split-K partials.
    char* w = (char*)d_ws;
    auto alloc = [&](size_t bytes) -> void* {
        void* p = (void*)w;
        w += (bytes + 255) & ~(size_t)255;
        return p;
    };
    bf16* regionA = (bf16*)alloc((size_t)BT_ * 2048 * sizeof(bf16));  // 32MB
    bf16* qkvb = regionA;                                // [BT][1024] (q|k)
    bf16* attn = regionA + (size_t)BT_ * 1024;           // [BT][512]
    bf16* hbuf = regionA + (size_t)BT_ * 1536;           // [BT][512] -> attn partial 0
    bf16* ff1  = regionA;                                // [BT][2048]
    bf16* x1     = (bf16*)alloc((size_t)BT_ * C_ * sizeof(bf16));
    bf16* h2     = (bf16*)alloc((size_t)BT_ * C_ * sizeof(bf16));    // attn p1 / W2 part0
    bf16* vt     = (bf16*)alloc((size_t)B_ * 512 * T_ * sizeof(bf16)); // W2 part1
    bf16* WqkvT  = (bf16*)alloc((size_t)1536 * C_ * sizeof(bf16));
    bf16* WoT    = (bf16*)alloc((size_t)C_ * C_ * sizeof(bf16));
    bf16* W1T    = (bf16*)alloc((size_t)C4_ * C_ * sizeof(bf16));
    bf16* W2T    = (bf16*)alloc((size_t)C_ * C4_ * sizeof(bf16));
    float* Lr    = (float*)alloc((size_t)B_ * H_ * T_ * sizeof(float));
    bf16* partK  = h2;  // h2(8MB)+vt(8MB) contiguous = 16MB bf16 partials

    // All weight transposes (fp32 -> bf16 [N][K]) in one launch
    transpose_all<<<768, 256, 0, stream>>>(Wq, Wk, Wv, Wo, W1, W2,
                                           WqkvT, WoT, W1T, W2T);
    // 1. h = LN(x)
    ln_kernel<float><<<BT_, 256, 0, stream>>>(x, g1, be1, hbuf);
    // 2. QKV GEMM: [8192,1536,512]; q,k -> qkvb, v -> vt (transposed)
    mfma_gemm<4><<<dim3(BT_ / 128, 1536 / 128), 256, 0, stream>>>(
        hbuf, WqkvT, nullptr, nullptr, qkvb, vt, BT_, 1536, C_);
    // 3. column-sum reciprocals (XCD-swizzled, 512 blocks)
    colsum_mfma<<<dim3(B_ * H_, 16), 512, 0, stream>>>(qkvb, Lr);
    // 4. attention output partials (XCD-swizzled, 512 blocks = 2/CU)
    attnout_mfma<<<dim3(B_ * H_, 16), 512, 0, stream>>>(qkvb, vt, Lr, hbuf, h2);
    // 4b. attn = p0 + p1
    reduce_attn<<<(BT_ * C_) / (256 * 8), 256, 0, stream>>>(hbuf, h2, attn);
    // 5. x1 = x + attn @ Wo + bo
    mfma_gemm2<<<dim3(BT_ / 128, C_ / 128), 512, 0, stream>>>(
        attn, WoT, bo, x, x1, BT_, C_, C_);
    // 6. h2 = LN(x1)
    ln_kernel<bf16><<<BT_, 256, 0, stream>>>(x1, g2, be2, h2);
    // 7. ff1 = relu(h2 @ W1 + b1)
    mfma_gemm<1><<<dim3(BT_ / 128, C4_ / 128), 256, 0, stream>>>(
        h2, W1T, b1, ff1, nullptr, nullptr, BT_, C4_, C_);
    // 8a. W2 split-K: partials (512 blocks -> 2/CU)
    mfma_gemm_sk<<<dim3(BT_ / 128, C_ / 128, 2), 256, 0, stream>>>(
        ff1, W2T, partK, BT_, C_, C4_, C4_ / 2);
    // 8b. out = p0 + p1 + b2 + x1
    reduce_w2<<<(BT_ * C_) / (256 * 4), 256, 0, stream>>>(partK, b2, x1, out);
}

// Round 12
// 255.855 us; speedup vs baseline: 1.0848x; 1.0742x over previous
//
#include <hip/hip_runtime.h>
#include <hip/hip_bf16.h>

// Block_4776003633552: transformer block, B=4 T=2048 C=512 H=8 D=64. fp32 I/O.
// Reference quirks: scale = C^-0.5; softmax over QUERY axis (axis=-2) =>
//   out_t = sum_{s<=t} exp(sc*q_t.k_s) * v_s / L_s,  L_s = sum_{t>=s} exp(sc*q_t.k_s).
// Round 12: GEMM K-loops -> BK=64 (half the barrier drains/FLOP, LDS 32KB) with
// XOR-swizzled LDS (lane stages global chunk (L&7)^(L>>3); reads use
// ((k*4+quad)^(lm&7)) -> ds_read_b128 2-way aliasing only, was ~8-way).
// transpose_all + LN1 merged into one prep launch. Attention unchanged (r11).

typedef __hip_bfloat16 bf16;
typedef __bf16 b8v __attribute__((ext_vector_type(8)));   // MFMA A/B fragment (8 bf16)
typedef float  f32x4 __attribute__((ext_vector_type(4))); // MFMA C/D fragment
typedef short  s8v  __attribute__((ext_vector_type(8)));  // 16B bf16 copy chunk
typedef short  s4v  __attribute__((ext_vector_type(4)));  // 8B packed chunk

#define B_   4
#define T_   2048
#define C_   512
#define H_   8
#define D_   64
#define BT_  (B_ * T_)
#define C4_  (4 * C_)
#define EPS_ 1e-5f
#define SCALE2_ 0.06375872465908385f  // (1/sqrt(512)) * log2(e): exp(x*s)=2^(x*s*log2e)

#define MFMA16(a, b, c) __builtin_amdgcn_mfma_f32_16x16x32_bf16(a, b, c, 0, 0, 0)
#define EXP2F(x) __builtin_amdgcn_exp2f(x)

static __device__ __forceinline__ float b2f(bf16 x) { return __bfloat162float(x); }
static __device__ __forceinline__ bf16  f2b(float x) { return __float2bfloat16(x); }
static __device__ __forceinline__ short f2bs(float x) {
    bf16 h = f2b(x);
    return __builtin_bit_cast(short, h);
}
static __device__ __forceinline__ float s2f(short x) {
    return b2f(__builtin_bit_cast(bf16, x));
}
// packed 2xfp32 -> 2xbf16 (v_cvt_pk_bf16_f32); memcpy because __hip_bfloat162
// is not trivially copyable (bit_cast rejected).
static __device__ __forceinline__ unsigned int pk2(float a, float b) {
    float2 f;
    f.x = a;
    f.y = b;
    __hip_bfloat162 h = __float22bfloat162_rn(f);
    unsigned int u;
    __builtin_memcpy(&u, &h, 4);
    return u;
}

// ---------------- LayerNorm over C=512, one block per row ----------------
static __device__ __forceinline__ float ldv(const float* p) { return *p; }
static __device__ __forceinline__ float ldv(const bf16* p)  { return b2f(*p); }

template <typename TIN>
static __device__ __forceinline__ void ln_body(const TIN* __restrict__ xr,
                                               const float* __restrict__ g,
                                               const float* __restrict__ be,
                                               bf16* __restrict__ orow,
                                               float* ws, float* wsq) {
    const int tid = threadIdx.x;
    float v0 = ldv(xr + tid * 2);
    float v1 = ldv(xr + tid * 2 + 1);
    float s = v0 + v1;
    float sq = v0 * v0 + v1 * v1;
    #pragma unroll
    for (int o = 32; o > 0; o >>= 1) {
        s += __shfl_down(s, o);
        sq += __shfl_down(sq, o);
    }
    const int wid = tid >> 6, lane = tid & 63;
    if (lane == 0) { ws[wid] = s; wsq[wid] = sq; }
    __syncthreads();
    if (tid == 0) {
        float ts = 0.f, tq = 0.f;
        #pragma unroll
        for (int i = 0; i < 4; i++) { ts += ws[i]; tq += wsq[i]; }
        float mu = ts * (1.f / C_);
        float var = tq * (1.f / C_) - mu * mu;
        ws[4] = mu;
        wsq[4] = rsqrtf(var + EPS_);
    }
    __syncthreads();
    const float mu = ws[4], rstd = wsq[4];
    orow[tid * 2]     = f2b((v0 - mu) * rstd * g[tid * 2]     + be[tid * 2]);
    orow[tid * 2 + 1] = f2b((v1 - mu) * rstd * g[tid * 2 + 1] + be[tid * 2 + 1]);
}

template <typename TIN>
__global__ __launch_bounds__(256) void ln_kernel(const TIN* __restrict__ x,
                                                 const float* __restrict__ g,
                                                 const float* __restrict__ be,
                                                 bf16* __restrict__ out) {
    __shared__ float ws[8], wsq[8];
    const int row = blockIdx.x;
    ln_body(x + (size_t)row * C_, g, be, out + (size_t)row * C_, ws, wsq);
}

// ---------------- prep: all weight transposes (768 blocks) + LN1 (8192) ----------------
__global__ __launch_bounds__(256) void prep_kernel(const float* __restrict__ Wq,
                                                   const float* __restrict__ Wk,
                                                   const float* __restrict__ Wv,
                                                   const float* __restrict__ Wo,
                                                   const float* __restrict__ W1,
                                                   const float* __restrict__ W2,
                                                   bf16* __restrict__ WqkvT,
                                                   bf16* __restrict__ WoT,
                                                   bf16* __restrict__ W1T,
                                                   bf16* __restrict__ W2T,
                                                   const float* __restrict__ x,
                                                   const float* __restrict__ g1,
                                                   const float* __restrict__ be1,
                                                   bf16* __restrict__ hbuf) {
    __shared__ float Ts[64][65];
    __shared__ float ws[8], wsq[8];
    const int tid = threadIdx.x;
    const int id = blockIdx.x;
    if (id >= 768) {  // LN1
        const int row = id - 768;
        ln_body(x + (size_t)row * C_, g1, be1, hbuf + (size_t)row * C_, ws, wsq);
        return;
    }
    if (id < 192) {
        const int sub = id / 64, rem = id % 64;
        const int xx = rem & 7, hh = rem >> 3;
        const float* src = (sub == 0 ? Wq : sub == 1 ? Wk : Wv) + (size_t)hh * C_ * D_;
        bf16* dst = WqkvT + (size_t)sub * 512 * C_;
        const int c0 = xx * 64;
        #pragma unroll
        for (int p = 0; p < 16; p++) {
            int idx = p * 256 + tid, i = idx >> 6, j = idx & 63;
            Ts[i][j] = src[(size_t)(c0 + i) * D_ + j];
        }
        __syncthreads();
        #pragma unroll
        for (int p = 0; p < 16; p++) {
            int idx = p * 256 + tid, j = idx >> 6, i = idx & 63;
            dst[(size_t)(hh * 64 + j) * C_ + c0 + i] = f2b(Ts[i][j]);
        }
    } else {
        const float* src;
        bf16* dst;
        int r0, c0, R, Cc;
        if (id < 256) {
            int rem = id - 192;
            src = Wo; dst = WoT; R = 512; Cc = 512;
            r0 = (rem & 7) * 64; c0 = (rem >> 3) * 64;
        } else if (id < 512) {
            int rem = id - 256;
            src = W1; dst = W1T; R = 512; Cc = 2048;
            r0 = (rem & 7) * 64; c0 = (rem >> 3) * 64;
        } else {
            int rem = id - 512;
            src = W2; dst = W2T; R = 2048; Cc = 512;
            r0 = (rem & 31) * 64; c0 = (rem >> 5) * 64;
        }
        #pragma unroll
        for (int p = 0; p < 16; p++) {
            int idx = p * 256 + tid, i = idx >> 6, j = idx & 63;
            Ts[i][j] = src[(size_t)(r0 + i) * Cc + c0 + j];
        }
        __syncthreads();
        #pragma unroll
        for (int p = 0; p < 16; p++) {
            int idx = p * 256 + tid, j = idx >> 6, i = idx & 63;
            dst[(size_t)(c0 + j) * R + r0 + i] = f2b(Ts[i][j]);
        }
    }
}

// ---------------- MFMA GEMM (256 thr): C[M,N] = A[M,K] @ Bt[N,K]^T ----------------
// 128x128 tile, BK=64, XOR-swizzled LDS. 4 waves (2x2 of 64x64), 32 MFMA/iter.
// MODE 1: +bias +relu -> bf16.  MODE 4: QKV split (q,k -> qkvb; v -> vt).
template <int MODE>
__global__ __launch_bounds__(256) void mfma_gemm(const bf16* __restrict__ A,
                                                 const bf16* __restrict__ Bt,
                                                 const float* __restrict__ bias,
                                                 bf16* __restrict__ outb,
                                                 bf16* __restrict__ qkvb,
                                                 bf16* __restrict__ vt,
                                                 int M, int N, int K) {
    __shared__ short As[128 * 64];
    __shared__ short Bs[128 * 64];
    const int tid = threadIdx.x;
    const int lane = tid & 63, wv = tid >> 6;
    const int wm = wv >> 1, wn = wv & 1;
    const int m0 = blockIdx.x * 128, n0 = blockIdx.y * 128;
    const int lrow8 = lane >> 3;              // row within 8-row band
    const int gchunk = ((lane & 7) ^ lrow8) * 8;  // swizzled global chunk (shorts)
    const int lm = lane & 15, quad = lane >> 4;
    const int sw = lm & 7;                    // read-side swizzle key

    f32x4 acc[4][4];
    #pragma unroll
    for (int r = 0; r < 4; r++)
        #pragma unroll
        for (int c = 0; c < 4; c++) {
            f32x4 z = {0.f, 0.f, 0.f, 0.f};
            acc[r][c] = z;
        }

    for (int k0 = 0; k0 < K; k0 += 64) {
        #pragma unroll
        for (int cc = 0; cc < 4; cc++) {
            const int rb = wv * 32 + cc * 8;  // wave-uniform base row
            const bf16* ga = A + (size_t)(m0 + rb + lrow8) * K + k0 + gchunk;
            __builtin_amdgcn_global_load_lds(
                (const __attribute__((address_space(1))) void*)ga,
                (__attribute__((address_space(3))) void*)&As[rb * 64], 16, 0, 0);
            const bf16* gb = Bt + (size_t)(n0 + rb + lrow8) * K + k0 + gchunk;
            __builtin_amdgcn_global_load_lds(
                (const __attribute__((address_space(1))) void*)gb,
                (__attribute__((address_space(3))) void*)&Bs[rb * 64], 16, 0, 0);
        }
        __syncthreads();
        b8v af[4][2], bfr[4][2];
        #pragma unroll
        for (int r = 0; r < 4; r++)
            #pragma unroll
            for (int k = 0; k < 2; k++)
                af[r][k] = *(const b8v*)&As[(wm * 64 + r * 16 + lm) * 64 +
                                            (((k * 4 + quad) ^ sw) * 8)];
        #pragma unroll
        for (int c = 0; c < 4; c++)
            #pragma unroll
            for (int k = 0; k < 2; k++)
                bfr[c][k] = *(const b8v*)&Bs[(wn * 64 + c * 16 + lm) * 64 +
                                             (((k * 4 + quad) ^ sw) * 8)];
        #pragma unroll
        for (int r = 0; r < 4; r++)
            #pragma unroll
            for (int c = 0; c < 4; c++) {
                acc[r][c] = MFMA16(af[r][0], bfr[c][0], acc[r][c]);
                acc[r][c] = MFMA16(af[r][1], bfr[c][1], acc[r][c]);
            }
        __syncthreads();
    }

    #pragma unroll
    for (int r = 0; r < 4; r++) {
        const int mbase = m0 + wm * 64 + r * 16 + quad * 4;
        #pragma unroll
        for (int c = 0; c < 4; c++) {
            const int n = n0 + wn * 64 + c * 16 + lm;
            #pragma unroll
            for (int reg = 0; reg < 4; reg++) {
                const int m = mbase + reg;
                float v = acc[r][c][reg];
                if (MODE == 1) {
                    v += bias[n];
                    v = fmaxf(v, 0.f);
                    outb[(size_t)m * N + n] = f2b(v);
                } else {  // MODE 4: QKV
                    if (n < 1024) {
                        qkvb[(size_t)m * 1024 + n] = f2b(v);
                    } else {
                        vt[((size_t)(m >> 11) * 512 + (n - 1024)) * T_ + (m & (T_ - 1))] =
                            f2b(v);
                    }
                }
            }
        }
    }
}

// ---------------- Split-K MFMA GEMM: partial[z] = A[:, zKh:(z+1)Kh] @ Bt^T ----------------
// BK=64 XOR-swizzled, same structure as mfma_gemm.
__global__ __launch_bounds__(256) void mfma_gemm_sk(const bf16* __restrict__ A,
                                                    const bf16* __restrict__ Bt,
                                                    bf16* __restrict__ part,
                                                    int M, int N, int K, int Khalf) {
    __shared__ short As[128 * 64];
    __shared__ short Bs[128 * 64];
    const int tid = threadIdx.x;
    const int lane = tid & 63, wv = tid >> 6;
    const int wm = wv >> 1, wn = wv & 1;
    const int m0 = blockIdx.x * 128, n0 = blockIdx.y * 128;
    const int kbase = blockIdx.z * Khalf;
    const int lrow8 = lane >> 3;
    const int gchunk = ((lane & 7) ^ lrow8) * 8;
    const int lm = lane & 15, quad = lane >> 4;
    const int sw = lm & 7;

    f32x4 acc[4][4];
    #pragma unroll
    for (int r = 0; r < 4; r++)
        #pragma unroll
        for (int c = 0; c < 4; c++) {
            f32x4 z = {0.f, 0.f, 0.f, 0.f};
            acc[r][c] = z;
        }

    for (int kk = 0; kk < Khalf; kk += 64) {
        const int k0 = kbase + kk;
        #pragma unroll
        for (int cc = 0; cc < 4; cc++) {
            const int rb = wv * 32 + cc * 8;
            const bf16* ga = A + (size_t)(m0 + rb + lrow8) * K + k0 + gchunk;
            __builtin_amdgcn_global_load_lds(
                (const __attribute__((address_space(1))) void*)ga,
                (__attribute__((address_space(3))) void*)&As[rb * 64], 16, 0, 0);
            const bf16* gb = Bt + (size_t)(n0 + rb + lrow8) * K + k0 + gchunk;
            __builtin_amdgcn_global_load_lds(
                (const __attribute__((address_space(1))) void*)gb,
                (__attribute__((address_space(3))) void*)&Bs[rb * 64], 16, 0, 0);
        }
        __syncthreads();
        b8v af[4][2], bfr[4][2];
        #pragma unroll
        for (int r = 0; r < 4; r++)
            #pragma unroll
            for (int k = 0; k < 2; k++)
                af[r][k] = *(const b8v*)&As[(wm * 64 + r * 16 + lm) * 64 +
                                            (((k * 4 + quad) ^ sw) * 8)];
        #pragma unroll
        for (int c = 0; c < 4; c++)
            #pragma unroll
            for (int k = 0; k < 2; k++)
                bfr[c][k] = *(const b8v*)&Bs[(wn * 64 + c * 16 + lm) * 64 +
                                             (((k * 4 + quad) ^ sw) * 8)];
        #pragma unroll
        for (int r = 0; r < 4; r++)
            #pragma unroll
            for (int c = 0; c < 4; c++) {
                acc[r][c] = MFMA16(af[r][0], bfr[c][0], acc[r][c]);
                acc[r][c] = MFMA16(af[r][1], bfr[c][1], acc[r][c]);
            }
        __syncthreads();
    }

    bf16* pz = part + (size_t)blockIdx.z * M * N;
    #pragma unroll
    for (int r = 0; r < 4; r++) {
        const int mbase = m0 + wm * 64 + r * 16 + quad * 4;
        #pragma unroll
        for (int c = 0; c < 4; c++) {
            const int n = n0 + wn * 64 + c * 16 + lm;
            #pragma unroll
            for (int reg = 0; reg < 4; reg++)
                pz[(size_t)(mbase + reg) * N + n] = f2b(acc[r][c][reg]);
        }
    }
}

// ---------------- reduce: out = p0 + p1 + bias + res (fp32 out) ----------------
__global__ __launch_bounds__(256) void reduce_w2(const bf16* __restrict__ part,
                                                 const float* __restrict__ bias,
                                                 const bf16* __restrict__ res,
                                                 float* __restrict__ out) {
    const size_t i = ((size_t)blockIdx.x * 256 + threadIdx.x) * 4;
    const int n = (int)(i & (C_ - 1));
    s4v a = *(const s4v*)(part + i);
    s4v b = *(const s4v*)(part + (size_t)BT_ * C_ + i);
    s4v rv = *(const s4v*)(res + i);
    float4 bs = *(const float4*)(bias + n);
    float4 o;
    o.x = s2f(a[0]) + s2f(b[0]) + bs.x + s2f(rv[0]);
    o.y = s2f(a[1]) + s2f(b[1]) + bs.y + s2f(rv[1]);
    o.z = s2f(a[2]) + s2f(b[2]) + bs.z + s2f(rv[2]);
    o.w = s2f(a[3]) + s2f(b[3]) + bs.w + s2f(rv[3]);
    *(float4*)(out + i) = o;
}

// ---------------- reduce: attn = p0 + p1 (bf16) ----------------
__global__ __launch_bounds__(256) void reduce_attn(const bf16* __restrict__ p0,
                                                   const bf16* __restrict__ p1,
                                                   bf16* __restrict__ attn) {
    const size_t i = ((size_t)blockIdx.x * 256 + threadIdx.x) * 8;
    s8v a = *(const s8v*)(p0 + i);
    s8v b = *(const s8v*)(p1 + i);
    s8v o;
    #pragma unroll
    for (int j = 0; j < 8; j++) o[j] = f2bs(s2f(a[j]) + s2f(b[j]));
    *(s8v*)(attn + i) = o;
}

// ---------------- MFMA GEMM (512 thr): Wo (+bias +fp32 res -> bf16) ----------------
// BK=64 XOR-swizzled. 8 waves (2m x 4n), each 64x32.
__global__ __launch_bounds__(512) void mfma_gemm2(const bf16* __restrict__ A,
                                                  const bf16* __restrict__ Bt,
                                                  const float* __restrict__ bias,
                                                  const float* __restrict__ resf,
                                                  bf16* __restrict__ outb,
                                                  int M, int N, int K) {
    __shared__ short As[128 * 64];
    __shared__ short Bs[128 * 64];
    const int tid = threadIdx.x;
    const int lane = tid & 63, wv = tid >> 6;       // 8 waves
    const int wm = wv >> 2, wn = wv & 3;            // 2 x 4
    const int m0 = blockIdx.x * 128, n0 = blockIdx.y * 128;
    const int lrow8 = lane >> 3;
    const int gchunk = ((lane & 7) ^ lrow8) * 8;
    const int lm = lane & 15, quad = lane >> 4;
    const int sw = lm & 7;

    f32x4 acc[4][2];
    #pragma unroll
    for (int r = 0; r < 4; r++)
        #pragma unroll
        for (int c = 0; c < 2; c++) {
            f32x4 z = {0.f, 0.f, 0.f, 0.f};
            acc[r][c] = z;
        }

    for (int k0 = 0; k0 < K; k0 += 64) {
        #pragma unroll
        for (int cc = 0; cc < 2; cc++) {
            const int rb = wv * 16 + cc * 8;
            const bf16* ga = A + (size_t)(m0 + rb + lrow8) * K + k0 + gchunk;
            __builtin_amdgcn_global_load_lds(
                (const __attribute__((address_space(1))) void*)ga,
                (__attribute__((address_space(3))) void*)&As[rb * 64], 16, 0, 0);
            const bf16* gb = Bt + (size_t)(n0 + rb + lrow8) * K + k0 + gchunk;
            __builtin_amdgcn_global_load_lds(
                (const __attribute__((address_space(1))) void*)gb,
                (__attribute__((address_space(3))) void*)&Bs[rb * 64], 16, 0, 0);
        }
        __syncthreads();
        b8v af[4][2], bfr[2][2];
        #pragma unroll
        for (int r = 0; r < 4; r++)
            #pragma unroll
            for (int k = 0; k < 2; k++)
                af[r][k] = *(const b8v*)&As[(wm * 64 + r * 16 + lm) * 64 +
                                            (((k * 4 + quad) ^ sw) * 8)];
        #pragma unroll
        for (int c = 0; c < 2; c++)
            #pragma unroll
            for (int k = 0; k < 2; k++)
                bfr[c][k] = *(const b8v*)&Bs[(wn * 32 + c * 16 + lm) * 64 +
                                             (((k * 4 + quad) ^ sw) * 8)];
        #pragma unroll
        for (int r = 0; r < 4; r++)
            #pragma unroll
            for (int c = 0; c < 2; c++) {
                acc[r][c] = MFMA16(af[r][0], bfr[c][0], acc[r][c]);
                acc[r][c] = MFMA16(af[r][1], bfr[c][1], acc[r][c]);
            }
        __syncthreads();
    }

    #pragma unroll
    for (int r = 0; r < 4; r++) {
        const int mbase = m0 + wm * 64 + r * 16 + quad * 4;
        #pragma unroll
        for (int c = 0; c < 2; c++) {
            const int n = n0 + wn * 32 + c * 16 + lm;
            #pragma unroll
            for (int reg = 0; reg < 4; reg++) {
                const int m = mbase + reg;
                float v = acc[r][c][reg] + bias[n] + resf[(size_t)m * N + n];
                outb[(size_t)m * N + n] = f2b(v);
            }
        }
    }
}

// ---------------- Pass 1: Lr[s] = 1 / sum_{t>=s} exp(sc*q_t.k_s) ----------------
// 64-key strips, pairs {i,31-i} -> grid (32 bh, 16 pairs) = 512 blocks, 33 iters
// each. Waves 4(t)x2(s-half). K frags strip-resident in registers. LDS ~29KB.
__global__ __launch_bounds__(512) void colsum_mfma(const bf16* __restrict__ qkv,
                                                   float* __restrict__ Lr) {
    __shared__ short Ks[64 * 72];
    __shared__ short Qs[2][64 * 72];
    __shared__ float red[4][64];
    const int tid = threadIdx.x, lane = tid & 63, wv = tid >> 6;
    const int wq = wv >> 1, wk = wv & 1;
    const int lm = lane & 15, quad = lane >> 4;
    const int bh = blockIdx.x, bb = bh >> 3, hh = bh & 7;
    const bf16* qbase = qkv + (size_t)bb * T_ * 1024 + hh * 64;
    const bf16* kbase = qbase + 512;
    const int r_ = tid >> 3, ch = tid & 7;
    for (int half = 0; half < 2; half++) {
        const int strip = half ? 31 - (int)blockIdx.y : (int)blockIdx.y;
        const int s0 = strip * 64;
        *(s8v*)&Ks[r_ * 72 + ch * 8] =
            *(const s8v*)(kbase + (size_t)(s0 + r_) * 1024 + ch * 8);
        s8v qr = *(const s8v*)(qbase + (size_t)(s0 + r_) * 1024 + ch * 8);
        b8v bk[2][2];
        float csum[2] = {};
        const int niter = 32 - strip;
        for (int it = 0; it < niter; it++) {
            const int buf = it & 1;
            *(s8v*)&Qs[buf][r_ * 72 + ch * 8] = qr;
            __syncthreads();
            if (it == 0) {
                #pragma unroll
                for (int c = 0; c < 2; c++)
                    #pragma unroll
                    for (int k = 0; k < 2; k++)
                        bk[c][k] = *(const b8v*)&Ks[(wk * 32 + c * 16 + lm) * 72 +
                                                    k * 32 + quad * 8];
            }
            if (it + 1 < niter) {
                const int t1 = s0 + (it + 1) * 64;
                qr = *(const s8v*)(qbase + (size_t)(t1 + r_) * 1024 + ch * 8);
            }
            const int t0 = s0 + it * 64;
            b8v aq[2];
            #pragma unroll
            for (int k = 0; k < 2; k++)
                aq[k] = *(const b8v*)&Qs[buf][(wq * 16 + lm) * 72 + k * 32 + quad * 8];
            if (it == 0) {  // diagonal: causal mask needed
                #pragma unroll
                for (int c = 0; c < 2; c++) {
                    f32x4 S = {0.f, 0.f, 0.f, 0.f};
                    S = MFMA16(aq[0], bk[c][0], S);
                    S = MFMA16(aq[1], bk[c][1], S);
                    const int s = s0 + wk * 32 + c * 16 + lm;
                    #pragma unroll
                    for (int reg = 0; reg < 4; reg++) {
                        int t = t0 + wq * 16 + quad * 4 + reg;
                        if (t >= s) csum[c] += EXP2F(S[reg] * SCALE2_);
                    }
                }
            } else {  // strictly below diagonal: no mask
                #pragma unroll
                for (int c = 0; c < 2; c++) {
                    f32x4 S = {0.f, 0.f, 0.f, 0.f};
                    S = MFMA16(aq[0], bk[c][0], S);
                    S = MFMA16(aq[1], bk[c][1], S);
                    csum[c] += EXP2F(S[0] * SCALE2_) + EXP2F(S[1] * SCALE2_) +
                               EXP2F(S[2] * SCALE2_) + EXP2F(S[3] * SCALE2_);
                }
            }
        }
        __syncthreads();
        #pragma unroll
        for (int c = 0; c < 2; c++) {
            float v = csum[c];
            v += __shfl_xor(v, 16);
            v += __shfl_xor(v, 32);
            if (lane < 16) red[wq][wk * 32 + c * 16 + lane] = v;
        }
        __syncthreads();
        if (tid < 64) {
            float s = red[0][tid] + red[1][tid] + red[2][tid] + red[3][tid];
            Lr[(size_t)bh * T_ + s0 + tid] = 1.0f / s;
        }
        __syncthreads();
    }
}

// ---------------- Pass 2: out_t = sum_{s<=t} exp(sc*q_t.k_s) * (v_s * Lr_s) ----------------
// 128-query strips, pairs {p,15-p}; each block handles even OR odd 64-key tiles
// (parity) -> 512 blocks, 17 iters each. LDS arena 72KB (Ored aliased onto dead
// K/V dbuf) -> 2 blocks/CU. Partial O -> p0/p1, merged by reduce_attn.
__global__ __launch_bounds__(512) void attnout_mfma(const bf16* __restrict__ qkv,
                                                    const bf16* __restrict__ vt,
                                                    const float* __restrict__ Lr,
                                                    bf16* __restrict__ pout0,
                                                    bf16* __restrict__ pout1) {
    __shared__ __align__(16) char arena[73728];
    short* const Qs = (short*)arena;                 // [128*72] 18432 B
    short* const Ps = (short*)(arena + 18432);       // [128*72] 18432 B
    short* const KV = (short*)(arena + 36864);       // Ks[2][64*72] Vt[2][64*72] 36864 B
    float* const Ored = (float*)(arena + 36864);     // [64*132] 33792 B (aliases KV)
    const int tid = threadIdx.x, lane = tid & 63, wv = tid >> 6;
    const int wm = wv >> 1, wn = wv & 1;
    const int lm = lane & 15, quad = lane >> 4;
    const int bh = blockIdx.x, bb = bh >> 3, hh = bh & 7;
    const int pairIdx = blockIdx.y >> 1, parity = blockIdx.y & 1;
    bf16* const outP = parity ? pout1 : pout0;
    const bf16* qbase = qkv + (size_t)bb * T_ * 1024 + hh * 64;
    const bf16* kbase = qbase + 512;
    const bf16* vtb = vt + ((size_t)bb * 512 + hh * 64) * T_;
    const float* Lrb = Lr + (size_t)bh * T_;
    const int r_ = tid >> 3, ch = tid & 7;
    for (int half = 0; half < 2; half++) {
        const int strip = half ? 15 - pairIdx : pairIdx;
        const int tb = strip * 128;
        #pragma unroll
        for (int cc = 0; cc < 2; cc++) {
            int idx = cc * 512 + tid, qr = idx >> 3, qc = idx & 7;
            *(s8v*)&Qs[qr * 72 + qc * 8] =
                *(const s8v*)(qbase + (size_t)(tb + qr) * 1024 + qc * 8);
        }
        int s0 = parity * 64;
        s8v kreg = *(const s8v*)(kbase + (size_t)(s0 + r_) * 1024 + ch * 8);
        s8v vreg = *(const s8v*)(vtb + (size_t)r_ * T_ + s0 + ch * 8);
        float4 lr0 = *(const float4*)(Lrb + s0 + ch * 8);
        float4 lr1 = *(const float4*)(Lrb + s0 + ch * 8 + 4);
        b8v bq[2][2];
        f32x4 o[2][4];
        #pragma unroll
        for (int r = 0; r < 2; r++)
            #pragma unroll
            for (int c = 0; c < 4; c++) {
                f32x4 z = {0.f, 0.f, 0.f, 0.f};
                o[r][c] = z;
            }
        const int niter = strip + 1;
        for (int it = 0; it < niter; it++) {
            s0 = (parity + 2 * it) * 64;
            const int buf = it & 1;
            short* const Ksb = KV + buf * (64 * 72);
            short* const Vsb = KV + 2 * (64 * 72) + buf * (64 * 72);
            uint4 vs;
            vs.x = pk2(s2f(vreg[0]) * lr0.x, s2f(vreg[1]) * lr0.y);
            vs.y = pk2(s2f(vreg[2]) * lr0.z, s2f(vreg[3]) * lr0.w);
            vs.z = pk2(s2f(vreg[4]) * lr1.x, s2f(vreg[5]) * lr1.y);
            vs.w = pk2(s2f(vreg[6]) * lr1.z, s2f(vreg[7]) * lr1.w);
            *(s8v*)&Ksb[r_ * 72 + ch * 8] = kreg;
            *(uint4*)&Vsb[r_ * 72 + ch * 8] = vs;
            __syncthreads();
            if (it == 0) {
                #pragma unroll
                for (int r = 0; r < 2; r++)
                    #pragma unroll
                    for (int k = 0; k < 2; k++)
                        bq[r][k] = *(const b8v*)&Qs[(wm * 32 + r * 16 + lm) * 72 +
                                                    k * 32 + quad * 8];
            }
            if (it + 1 < niter) {
                const int s1 = s0 + 128;
                kreg = *(const s8v*)(kbase + (size_t)(s1 + r_) * 1024 + ch * 8);
                vreg = *(const s8v*)(vtb + (size_t)r_ * T_ + s1 + ch * 8);
                lr0 = *(const float4*)(Lrb + s1 + ch * 8);
                lr1 = *(const float4*)(Lrb + s1 + ch * 8 + 4);
            }
            b8v ak[2][2];
            #pragma unroll
            for (int c = 0; c < 2; c++)
                #pragma unroll
                for (int k = 0; k < 2; k++)
                    ak[c][k] = *(const b8v*)&Ksb[(wn * 32 + c * 16 + lm) * 72 +
                                                 k * 32 + quad * 8];
            const bool masked = (it == niter - 1);
            #pragma unroll
            for (int r = 0; r < 2; r++) {
                const int t = tb + wm * 32 + r * 16 + lm;
                #pragma unroll
                for (int c = 0; c < 2; c++) {
                    f32x4 S = {0.f, 0.f, 0.f, 0.f};
                    S = MFMA16(ak[c][0], bq[r][0], S);
                    S = MFMA16(ak[c][1], bq[r][1], S);
                    float e[4];
                    #pragma unroll
                    for (int reg = 0; reg < 4; reg++)
                        e[reg] = EXP2F(S[reg] * SCALE2_);
                    if (masked) {
                        #pragma unroll
                        for (int reg = 0; reg < 4; reg++) {
                            int s = s0 + wn * 32 + c * 16 + quad * 4 + reg;
                            if (t < s) e[reg] = 0.f;
                        }
                    }
                    uint2 u;
                    u.x = pk2(e[0], e[1]);
                    u.y = pk2(e[2], e[3]);
                    *(uint2*)&Ps[(wm * 32 + r * 16 + lm) * 72 + wn * 32 + c * 16 +
                                 quad * 4] = u;
                }
            }
            #pragma unroll
            for (int r = 0; r < 2; r++) {
                b8v ap = *(const b8v*)&Ps[(wm * 32 + r * 16 + lm) * 72 + wn * 32 +
                                          quad * 8];
                #pragma unroll
                for (int c = 0; c < 4; c++) {
                    b8v bv = *(const b8v*)&Vsb[(c * 16 + lm) * 72 + wn * 32 + quad * 8];
                    o[r][c] = MFMA16(ap, bv, o[r][c]);
                }
            }
        }
        __syncthreads();
        if (wn == 1) {
            #pragma unroll
            for (int r = 0; r < 2; r++)
                #pragma unroll
                for (int c = 0; c < 4; c++)
                    *(f32x4*)&Ored[(c * 16 + lm) * 132 + wm * 32 + r * 16 + quad * 4] =
                        o[r][c];
        }
        __syncthreads();
        if (wn == 0) {
            #pragma unroll
            for (int r = 0; r < 2; r++)
                #pragma unroll
                for (int c = 0; c < 4; c++) {
                    f32x4 p = *(const f32x4*)&Ored[(c * 16 + lm) * 132 + wm * 32 +
                                                   r * 16 + quad * 4];
                    #pragma unroll
                    for (int reg = 0; reg < 4; reg++)
                        outP[(size_t)(bb * T_ + tb + wm * 32 + r * 16 + quad * 4 +
                                      reg) * C_ + hh * 64 + c * 16 + lm] =
                            f2b(o[r][c][reg] + p[reg]);
                }
        }
        __syncthreads();
    }
}

extern "C" void kernel_launch(void* const* d_in, const int* in_sizes, int n_in,
                              void* d_out, int out_size, void* d_ws, size_t ws_size,
                              hipStream_t stream) {
    const float* x   = (const float*)d_in[0];
    const float* Wq  = (const float*)d_in[1];
    const float* Wk  = (const float*)d_in[2];
    const float* Wv  = (const float*)d_in[3];
    const float* Wo  = (const float*)d_in[4];
    const float* bo  = (const float*)d_in[5];
    const float* W1  = (const float*)d_in[6];
    const float* b1  = (const float*)d_in[7];
    const float* W2  = (const float*)d_in[8];
    const float* b2  = (const float*)d_in[9];
    const float* g1  = (const float*)d_in[10];
    const float* be1 = (const float*)d_in[11];
    const float* g2  = (const float*)d_in[12];
    const float* be2 = (const float*)d_in[13];
    float* out = (float*)d_out;

    char* w = (char*)d_ws;
    auto alloc = [&](size_t bytes) -> void* {
        void* p = (void*)w;
        w += (bytes + 255) & ~(size_t)255;
        return p;
    };
    bf16* regionA = (bf16*)alloc((size_t)BT_ * 2048 * sizeof(bf16));  // 32MB
    bf16* qkvb = regionA;                                // [BT][1024] (q|k)
    bf16* attn = regionA + (size_t)BT_ * 1024;           // [BT][512]
    bf16* hbuf = regionA + (size_t)BT_ * 1536;           // [BT][512] -> attn partial 0
    bf16* ff1  = regionA;                                // [BT][2048]
    bf16* x1     = (bf16*)alloc((size_t)BT_ * C_ * sizeof(bf16));
    bf16* h2     = (bf16*)alloc((size_t)BT_ * C_ * sizeof(bf16));    // attn p1 / W2 part0
    bf16* vt     = (bf16*)alloc((size_t)B_ * 512 * T_ * sizeof(bf16)); // W2 part1
    bf16* WqkvT  = (bf16*)alloc((size_t)1536 * C_ * sizeof(bf16));
    bf16* WoT    = (bf16*)alloc((size_t)C_ * C_ * sizeof(bf16));
    bf16* W1T    = (bf16*)alloc((size_t)C4_ * C_ * sizeof(bf16));
    bf16* W2T    = (bf16*)alloc((size_t)C_ * C4_ * sizeof(bf16));
    float* Lr    = (float*)alloc((size_t)B_ * H_ * T_ * sizeof(float));
    bf16* partK  = h2;  // h2(8MB)+vt(8MB) contiguous = 16MB bf16 partials

    // 0+1. weight transposes + LN1 in one launch
    prep_kernel<<<768 + BT_, 256, 0, stream>>>(Wq, Wk, Wv, Wo, W1, W2,
                                               WqkvT, WoT, W1T, W2T,
                                               x, g1, be1, hbuf);
    // 2. QKV GEMM: [8192,1536,512]; q,k -> qkvb, v -> vt (transposed)
    mfma_gemm<4><<<dim3(BT_ / 128, 1536 / 128), 256, 0, stream>>>(
        hbuf, WqkvT, nullptr, nullptr, qkvb, vt, BT_, 1536, C_);
    // 3. column-sum reciprocals (XCD-swizzled, 512 blocks)
    colsum_mfma<<<dim3(B_ * H_, 16), 512, 0, stream>>>(qkvb, Lr);
    // 4. attention output partials (XCD-swizzled, 512 blocks = 2/CU)
    attnout_mfma<<<dim3(B_ * H_, 16), 512, 0, stream>>>(qkvb, vt, Lr, hbuf, h2);
    // 4b. attn = p0 + p1
    reduce_attn<<<(BT_ * C_) / (256 * 8), 256, 0, stream>>>(hbuf, h2, attn);
    // 5. x1 = x + attn @ Wo + bo
    mfma_gemm2<<<dim3(BT_ / 128, C_ / 128), 512, 0, stream>>>(
        attn, WoT, bo, x, x1, BT_, C_, C_);
    // 6. h2 = LN(x1)
    ln_kernel<bf16><<<BT_, 256, 0, stream>>>(x1, g2, be2, h2);
    // 7. ff1 = relu(h2 @ W1 + b1)
    mfma_gemm<1><<<dim3(BT_ / 128, C4_ / 128), 256, 0, stream>>>(
        h2, W1T, b1, ff1, nullptr, nullptr, BT_, C4_, C_);
    // 8a. W2 split-K: partials (512 blocks -> 2/CU)
    mfma_gemm_sk<<<dim3(BT_ / 128, C_ / 128, 2), 256, 0, stream>>>(
        ff1, W2T, partK, BT_, C_, C4_, C4_ / 2);
    // 8b. out = p0 + p1 + b2 + x1
    reduce_w2<<<(BT_ * C_) / (256 * 4), 256, 0, stream>>>(partK, b2, x1, out);
}

// Round 13
// 245.584 us; speedup vs baseline: 1.1302x; 1.0418x over previous
//
#include <hip/hip_runtime.h>
#include <hip/hip_bf16.h>

// Block_4776003633552: transformer block, B=4 T=2048 C=512 H=8 D=64. fp32 I/O.
// Reference quirks: scale = C^-0.5; softmax over QUERY axis (axis=-2) =>
//   out_t = sum_{s<=t} exp(sc*q_t.k_s) * v_s / L_s,  L_s = sum_{t>=s} exp(sc*q_t.k_s).
// Round 13: reduce_attn fused into Wo GEMM (A = p0+p1 staged via VGPR add with
// one-iter reg prefetch; B stays on global_load_lds). QKV v-section epilogue
// LDS-transposes the tile (pitch 136) for coalesced 16B vt stores. Rest = r12
// (BK=64 XOR-swizzled GEMMs, parity-split attention, W2 split-K).

typedef __hip_bfloat16 bf16;
typedef __bf16 b8v __attribute__((ext_vector_type(8)));   // MFMA A/B fragment (8 bf16)
typedef float  f32x4 __attribute__((ext_vector_type(4))); // MFMA C/D fragment
typedef short  s8v  __attribute__((ext_vector_type(8)));  // 16B bf16 copy chunk
typedef short  s4v  __attribute__((ext_vector_type(4)));  // 8B packed chunk

#define B_   4
#define T_   2048
#define C_   512
#define H_   8
#define D_   64
#define BT_  (B_ * T_)
#define C4_  (4 * C_)
#define EPS_ 1e-5f
#define SCALE2_ 0.06375872465908385f  // (1/sqrt(512)) * log2(e): exp(x*s)=2^(x*s*log2e)

#define MFMA16(a, b, c) __builtin_amdgcn_mfma_f32_16x16x32_bf16(a, b, c, 0, 0, 0)
#define EXP2F(x) __builtin_amdgcn_exp2f(x)

static __device__ __forceinline__ float b2f(bf16 x) { return __bfloat162float(x); }
static __device__ __forceinline__ bf16  f2b(float x) { return __float2bfloat16(x); }
static __device__ __forceinline__ short f2bs(float x) {
    bf16 h = f2b(x);
    return __builtin_bit_cast(short, h);
}
static __device__ __forceinline__ float s2f(short x) {
    return b2f(__builtin_bit_cast(bf16, x));
}
// packed 2xfp32 -> 2xbf16 (v_cvt_pk_bf16_f32); memcpy because __hip_bfloat162
// is not trivially copyable (bit_cast rejected).
static __device__ __forceinline__ unsigned int pk2(float a, float b) {
    float2 f;
    f.x = a;
    f.y = b;
    __hip_bfloat162 h = __float22bfloat162_rn(f);
    unsigned int u;
    __builtin_memcpy(&u, &h, 4);
    return u;
}

// ---------------- LayerNorm over C=512, one block per row ----------------
static __device__ __forceinline__ float ldv(const float* p) { return *p; }
static __device__ __forceinline__ float ldv(const bf16* p)  { return b2f(*p); }

template <typename TIN>
static __device__ __forceinline__ void ln_body(const TIN* __restrict__ xr,
                                               const float* __restrict__ g,
                                               const float* __restrict__ be,
                                               bf16* __restrict__ orow,
                                               float* ws, float* wsq) {
    const int tid = threadIdx.x;
    float v0 = ldv(xr + tid * 2);
    float v1 = ldv(xr + tid * 2 + 1);
    float s = v0 + v1;
    float sq = v0 * v0 + v1 * v1;
    #pragma unroll
    for (int o = 32; o > 0; o >>= 1) {
        s += __shfl_down(s, o);
        sq += __shfl_down(sq, o);
    }
    const int wid = tid >> 6, lane = tid & 63;
    if (lane == 0) { ws[wid] = s; wsq[wid] = sq; }
    __syncthreads();
    if (tid == 0) {
        float ts = 0.f, tq = 0.f;
        #pragma unroll
        for (int i = 0; i < 4; i++) { ts += ws[i]; tq += wsq[i]; }
        float mu = ts * (1.f / C_);
        float var = tq * (1.f / C_) - mu * mu;
        ws[4] = mu;
        wsq[4] = rsqrtf(var + EPS_);
    }
    __syncthreads();
    const float mu = ws[4], rstd = wsq[4];
    orow[tid * 2]     = f2b((v0 - mu) * rstd * g[tid * 2]     + be[tid * 2]);
    orow[tid * 2 + 1] = f2b((v1 - mu) * rstd * g[tid * 2 + 1] + be[tid * 2 + 1]);
}

template <typename TIN>
__global__ __launch_bounds__(256) void ln_kernel(const TIN* __restrict__ x,
                                                 const float* __restrict__ g,
                                                 const float* __restrict__ be,
                                                 bf16* __restrict__ out) {
    __shared__ float ws[8], wsq[8];
    const int row = blockIdx.x;
    ln_body(x + (size_t)row * C_, g, be, out + (size_t)row * C_, ws, wsq);
}

// ---------------- prep: all weight transposes (768 blocks) + LN1 (8192) ----------------
__global__ __launch_bounds__(256) void prep_kernel(const float* __restrict__ Wq,
                                                   const float* __restrict__ Wk,
                                                   const float* __restrict__ Wv,
                                                   const float* __restrict__ Wo,
                                                   const float* __restrict__ W1,
                                                   const float* __restrict__ W2,
                                                   bf16* __restrict__ WqkvT,
                                                   bf16* __restrict__ WoT,
                                                   bf16* __restrict__ W1T,
                                                   bf16* __restrict__ W2T,
                                                   const float* __restrict__ x,
                                                   const float* __restrict__ g1,
                                                   const float* __restrict__ be1,
                                                   bf16* __restrict__ hbuf) {
    __shared__ float Ts[64][65];
    __shared__ float ws[8], wsq[8];
    const int tid = threadIdx.x;
    const int id = blockIdx.x;
    if (id >= 768) {  // LN1
        const int row = id - 768;
        ln_body(x + (size_t)row * C_, g1, be1, hbuf + (size_t)row * C_, ws, wsq);
        return;
    }
    if (id < 192) {
        const int sub = id / 64, rem = id % 64;
        const int xx = rem & 7, hh = rem >> 3;
        const float* src = (sub == 0 ? Wq : sub == 1 ? Wk : Wv) + (size_t)hh * C_ * D_;
        bf16* dst = WqkvT + (size_t)sub * 512 * C_;
        const int c0 = xx * 64;
        #pragma unroll
        for (int p = 0; p < 16; p++) {
            int idx = p * 256 + tid, i = idx >> 6, j = idx & 63;
            Ts[i][j] = src[(size_t)(c0 + i) * D_ + j];
        }
        __syncthreads();
        #pragma unroll
        for (int p = 0; p < 16; p++) {
            int idx = p * 256 + tid, j = idx >> 6, i = idx & 63;
            dst[(size_t)(hh * 64 + j) * C_ + c0 + i] = f2b(Ts[i][j]);
        }
    } else {
        const float* src;
        bf16* dst;
        int r0, c0, R, Cc;
        if (id < 256) {
            int rem = id - 192;
            src = Wo; dst = WoT; R = 512; Cc = 512;
            r0 = (rem & 7) * 64; c0 = (rem >> 3) * 64;
        } else if (id < 512) {
            int rem = id - 256;
            src = W1; dst = W1T; R = 512; Cc = 2048;
            r0 = (rem & 7) * 64; c0 = (rem >> 3) * 64;
        } else {
            int rem = id - 512;
            src = W2; dst = W2T; R = 2048; Cc = 512;
            r0 = (rem & 31) * 64; c0 = (rem >> 5) * 64;
        }
        #pragma unroll
        for (int p = 0; p < 16; p++) {
            int idx = p * 256 + tid, i = idx >> 6, j = idx & 63;
            Ts[i][j] = src[(size_t)(r0 + i) * Cc + c0 + j];
        }
        __syncthreads();
        #pragma unroll
        for (int p = 0; p < 16; p++) {
            int idx = p * 256 + tid, j = idx >> 6, i = idx & 63;
            dst[(size_t)(c0 + j) * R + r0 + i] = f2b(Ts[i][j]);
        }
    }
}

// ---------------- MFMA GEMM (256 thr): C[M,N] = A[M,K] @ Bt[N,K]^T ----------------
// 128x128 tile, BK=64, XOR-swizzled LDS. 4 waves (2x2 of 64x64), 32 MFMA/iter.
// MODE 1: +bias +relu -> bf16.  MODE 4: QKV split (q,k -> qkvb; v -> vt, with
// LDS-transposed coalesced vt stores).
template <int MODE>
__global__ __launch_bounds__(256) void mfma_gemm(const bf16* __restrict__ A,
                                                 const bf16* __restrict__ Bt,
                                                 const float* __restrict__ bias,
                                                 bf16* __restrict__ outb,
                                                 bf16* __restrict__ qkvb,
                                                 bf16* __restrict__ vt,
                                                 int M, int N, int K) {
    constexpr int LBSZ = (MODE == 4) ? (128 * 136) : (2 * 128 * 64);
    __shared__ __align__(16) short LB[LBSZ];
    short* const As = LB;
    short* const Bs = LB + 128 * 64;
    const int tid = threadIdx.x;
    const int lane = tid & 63, wv = tid >> 6;
    const int wm = wv >> 1, wn = wv & 1;
    const int m0 = blockIdx.x * 128, n0 = blockIdx.y * 128;
    const int lrow8 = lane >> 3;              // row within 8-row band
    const int gchunk = ((lane & 7) ^ lrow8) * 8;  // swizzled global chunk (shorts)
    const int lm = lane & 15, quad = lane >> 4;
    const int sw = lm & 7;                    // read-side swizzle key

    f32x4 acc[4][4];
    #pragma unroll
    for (int r = 0; r < 4; r++)
        #pragma unroll
        for (int c = 0; c < 4; c++) {
            f32x4 z = {0.f, 0.f, 0.f, 0.f};
            acc[r][c] = z;
        }

    for (int k0 = 0; k0 < K; k0 += 64) {
        #pragma unroll
        for (int cc = 0; cc < 4; cc++) {
            const int rb = wv * 32 + cc * 8;  // wave-uniform base row
            const bf16* ga = A + (size_t)(m0 + rb + lrow8) * K + k0 + gchunk;
            __builtin_amdgcn_global_load_lds(
                (const __attribute__((address_space(1))) void*)ga,
                (__attribute__((address_space(3))) void*)&As[rb * 64], 16, 0, 0);
            const bf16* gb = Bt + (size_t)(n0 + rb + lrow8) * K + k0 + gchunk;
            __builtin_amdgcn_global_load_lds(
                (const __attribute__((address_space(1))) void*)gb,
                (__attribute__((address_space(3))) void*)&Bs[rb * 64], 16, 0, 0);
        }
        __syncthreads();
        b8v af[4][2], bfr[4][2];
        #pragma unroll
        for (int r = 0; r < 4; r++)
            #pragma unroll
            for (int k = 0; k < 2; k++)
                af[r][k] = *(const b8v*)&As[(wm * 64 + r * 16 + lm) * 64 +
                                            (((k * 4 + quad) ^ sw) * 8)];
        #pragma unroll
        for (int c = 0; c < 4; c++)
            #pragma unroll
            for (int k = 0; k < 2; k++)
                bfr[c][k] = *(const b8v*)&Bs[(wn * 64 + c * 16 + lm) * 64 +
                                             (((k * 4 + quad) ^ sw) * 8)];
        #pragma unroll
        for (int r = 0; r < 4; r++)
            #pragma unroll
            for (int c = 0; c < 4; c++) {
                acc[r][c] = MFMA16(af[r][0], bfr[c][0], acc[r][c]);
                acc[r][c] = MFMA16(af[r][1], bfr[c][1], acc[r][c]);
            }
        __syncthreads();
    }

    if (MODE == 4 && n0 >= 1024) {
        // V section: LDS-transpose (pitch 136 shorts: 16B-aligned rows, <=2-way
        // banks) then coalesced 16B stores to vt[b][d][t].
        short* const trans = LB;  // 128 x 136 (K-loop's final barrier guards reuse)
        #pragma unroll
        for (int r = 0; r < 4; r++) {
            const int ml = wm * 64 + r * 16 + quad * 4;
            #pragma unroll
            for (int c = 0; c < 4; c++) {
                const int nl = wn * 64 + c * 16 + lm;
                s4v p;
                #pragma unroll
                for (int reg = 0; reg < 4; reg++) p[reg] = f2bs(acc[r][c][reg]);
                *(s4v*)&trans[nl * 136 + ml] = p;
            }
        }
        __syncthreads();
        const int bb = m0 >> 11, t0loc = m0 & (T_ - 1);
        #pragma unroll
        for (int itb = 0; itb < 8; itb++) {
            int id = itb * 256 + tid;
            int nr = id >> 4, mc = id & 15;
            s8v v = *(const s8v*)&trans[nr * 136 + mc * 8];
            *(s8v*)&vt[((size_t)bb * 512 + (n0 - 1024) + nr) * T_ + t0loc + mc * 8] = v;
        }
        return;
    }

    #pragma unroll
    for (int r = 0; r < 4; r++) {
        const int mbase = m0 + wm * 64 + r * 16 + quad * 4;
        #pragma unroll
        for (int c = 0; c < 4; c++) {
            const int n = n0 + wn * 64 + c * 16 + lm;
            #pragma unroll
            for (int reg = 0; reg < 4; reg++) {
                const int m = mbase + reg;
                float v = acc[r][c][reg];
                if (MODE == 1) {
                    v += bias[n];
                    v = fmaxf(v, 0.f);
                    outb[(size_t)m * N + n] = f2b(v);
                } else {  // MODE 4 q/k section
                    qkvb[(size_t)m * 1024 + n] = f2b(v);
                }
            }
        }
    }
}

// ---------------- Split-K MFMA GEMM: partial[z] = A[:, zKh:(z+1)Kh] @ Bt^T ----------------
__global__ __launch_bounds__(256) void mfma_gemm_sk(const bf16* __restrict__ A,
                                                    const bf16* __restrict__ Bt,
                                                    bf16* __restrict__ part,
                                                    int M, int N, int K, int Khalf) {
    __shared__ short As[128 * 64];
    __shared__ short Bs[128 * 64];
    const int tid = threadIdx.x;
    const int lane = tid & 63, wv = tid >> 6;
    const int wm = wv >> 1, wn = wv & 1;
    const int m0 = blockIdx.x * 128, n0 = blockIdx.y * 128;
    const int kbase = blockIdx.z * Khalf;
    const int lrow8 = lane >> 3;
    const int gchunk = ((lane & 7) ^ lrow8) * 8;
    const int lm = lane & 15, quad = lane >> 4;
    const int sw = lm & 7;

    f32x4 acc[4][4];
    #pragma unroll
    for (int r = 0; r < 4; r++)
        #pragma unroll
        for (int c = 0; c < 4; c++) {
            f32x4 z = {0.f, 0.f, 0.f, 0.f};
            acc[r][c] = z;
        }

    for (int kk = 0; kk < Khalf; kk += 64) {
        const int k0 = kbase + kk;
        #pragma unroll
        for (int cc = 0; cc < 4; cc++) {
            const int rb = wv * 32 + cc * 8;
            const bf16* ga = A + (size_t)(m0 + rb + lrow8) * K + k0 + gchunk;
            __builtin_amdgcn_global_load_lds(
                (const __attribute__((address_space(1))) void*)ga,
                (__attribute__((address_space(3))) void*)&As[rb * 64], 16, 0, 0);
            const bf16* gb = Bt + (size_t)(n0 + rb + lrow8) * K + k0 + gchunk;
            __builtin_amdgcn_global_load_lds(
                (const __attribute__((address_space(1))) void*)gb,
                (__attribute__((address_space(3))) void*)&Bs[rb * 64], 16, 0, 0);
        }
        __syncthreads();
        b8v af[4][2], bfr[4][2];
        #pragma unroll
        for (int r = 0; r < 4; r++)
            #pragma unroll
            for (int k = 0; k < 2; k++)
                af[r][k] = *(const b8v*)&As[(wm * 64 + r * 16 + lm) * 64 +
                                            (((k * 4 + quad) ^ sw) * 8)];
        #pragma unroll
        for (int c = 0; c < 4; c++)
            #pragma unroll
            for (int k = 0; k < 2; k++)
                bfr[c][k] = *(const b8v*)&Bs[(wn * 64 + c * 16 + lm) * 64 +
                                             (((k * 4 + quad) ^ sw) * 8)];
        #pragma unroll
        for (int r = 0; r < 4; r++)
            #pragma unroll
            for (int c = 0; c < 4; c++) {
                acc[r][c] = MFMA16(af[r][0], bfr[c][0], acc[r][c]);
                acc[r][c] = MFMA16(af[r][1], bfr[c][1], acc[r][c]);
            }
        __syncthreads();
    }

    bf16* pz = part + (size_t)blockIdx.z * M * N;
    #pragma unroll
    for (int r = 0; r < 4; r++) {
        const int mbase = m0 + wm * 64 + r * 16 + quad * 4;
        #pragma unroll
        for (int c = 0; c < 4; c++) {
            const int n = n0 + wn * 64 + c * 16 + lm;
            #pragma unroll
            for (int reg = 0; reg < 4; reg++)
                pz[(size_t)(mbase + reg) * N + n] = f2b(acc[r][c][reg]);
        }
    }
}

// ---------------- reduce: out = p0 + p1 + bias + res (fp32 out) ----------------
__global__ __launch_bounds__(256) void reduce_w2(const bf16* __restrict__ part,
                                                 const float* __restrict__ bias,
                                                 const bf16* __restrict__ res,
                                                 float* __restrict__ out) {
    const size_t i = ((size_t)blockIdx.x * 256 + threadIdx.x) * 4;
    const int n = (int)(i & (C_ - 1));
    s4v a = *(const s4v*)(part + i);
    s4v b = *(const s4v*)(part + (size_t)BT_ * C_ + i);
    s4v rv = *(const s4v*)(res + i);
    float4 bs = *(const float4*)(bias + n);
    float4 o;
    o.x = s2f(a[0]) + s2f(b[0]) + bs.x + s2f(rv[0]);
    o.y = s2f(a[1]) + s2f(b[1]) + bs.y + s2f(rv[1]);
    o.z = s2f(a[2]) + s2f(b[2]) + bs.z + s2f(rv[2]);
    o.w = s2f(a[3]) + s2f(b[3]) + bs.w + s2f(rv[3]);
    *(float4*)(out + i) = o;
}

// ---------------- MFMA GEMM (512 thr) fused: x1 = (p0+p1)@WoT^T + bias + res ----------------
// A = p0+p1 staged via VGPR add + ds_write (reg prefetch one iter ahead);
// B via global_load_lds. BK=64 XOR-swizzled. 8 waves (2m x 4n), each 64x32.
__global__ __launch_bounds__(512) void mfma_gemm2f(const bf16* __restrict__ p0,
                                                   const bf16* __restrict__ p1,
                                                   const bf16* __restrict__ Bt,
                                                   const float* __restrict__ bias,
                                                   const float* __restrict__ resf,
                                                   bf16* __restrict__ outb,
                                                   int M, int N, int K) {
    __shared__ short As[128 * 64];
    __shared__ short Bs[128 * 64];
    const int tid = threadIdx.x;
    const int lane = tid & 63, wv = tid >> 6;       // 8 waves
    const int wm = wv >> 2, wn = wv & 3;            // 2 x 4
    const int m0 = blockIdx.x * 128, n0 = blockIdx.y * 128;
    const int lrow8 = lane >> 3;
    const int gchunk = ((lane & 7) ^ lrow8) * 8;
    const int lm = lane & 15, quad = lane >> 4;
    const int sw = lm & 7;
    // A staging: 1024 16B-chunks, 2 per thread. LDS pos p of row r holds
    // global chunk p^(r&7) (same invariant as the DMA path).
    int arow[2], apos[2], asrc[2];
    #pragma unroll
    for (int cc = 0; cc < 2; cc++) {
        int id = cc * 512 + tid;
        arow[cc] = id >> 3;
        apos[cc] = id & 7;
        asrc[cc] = (apos[cc] ^ (arow[cc] & 7)) * 8;
    }

    f32x4 acc[4][2];
    #pragma unroll
    for (int r = 0; r < 4; r++)
        #pragma unroll
        for (int c = 0; c < 2; c++) {
            f32x4 z = {0.f, 0.f, 0.f, 0.f};
            acc[r][c] = z;
        }

    // preload A regs for iter 0
    s8v a0[2], a1[2];
    #pragma unroll
    for (int cc = 0; cc < 2; cc++) {
        a0[cc] = *(const s8v*)(p0 + (size_t)(m0 + arow[cc]) * K + asrc[cc]);
        a1[cc] = *(const s8v*)(p1 + (size_t)(m0 + arow[cc]) * K + asrc[cc]);
    }

    for (int k0 = 0; k0 < K; k0 += 64) {
        // sum partials and commit A tile
        #pragma unroll
        for (int cc = 0; cc < 2; cc++) {
            s8v s;
            #pragma unroll
            for (int j = 0; j < 8; j++) s[j] = f2bs(s2f(a0[cc][j]) + s2f(a1[cc][j]));
            *(s8v*)&As[arow[cc] * 64 + apos[cc] * 8] = s;
        }
        // issue B DMA
        #pragma unroll
        for (int cc = 0; cc < 2; cc++) {
            const int rb = wv * 16 + cc * 8;
            const bf16* gb = Bt + (size_t)(n0 + rb + lrow8) * K + k0 + gchunk;
            __builtin_amdgcn_global_load_lds(
                (const __attribute__((address_space(1))) void*)gb,
                (__attribute__((address_space(3))) void*)&Bs[rb * 64], 16, 0, 0);
        }
        __syncthreads();
        // prefetch next iter's A regs (overlaps MFMA below)
        if (k0 + 64 < K) {
            #pragma unroll
            for (int cc = 0; cc < 2; cc++) {
                a0[cc] = *(const s8v*)(p0 + (size_t)(m0 + arow[cc]) * K + k0 + 64 +
                                       asrc[cc]);
                a1[cc] = *(const s8v*)(p1 + (size_t)(m0 + arow[cc]) * K + k0 + 64 +
                                       asrc[cc]);
            }
        }
        b8v af[4][2], bfr[2][2];
        #pragma unroll
        for (int r = 0; r < 4; r++)
            #pragma unroll
            for (int k = 0; k < 2; k++)
                af[r][k] = *(const b8v*)&As[(wm * 64 + r * 16 + lm) * 64 +
                                            (((k * 4 + quad) ^ sw) * 8)];
        #pragma unroll
        for (int c = 0; c < 2; c++)
            #pragma unroll
            for (int k = 0; k < 2; k++)
                bfr[c][k] = *(const b8v*)&Bs[(wn * 32 + c * 16 + lm) * 64 +
                                             (((k * 4 + quad) ^ sw) * 8)];
        #pragma unroll
        for (int r = 0; r < 4; r++)
            #pragma unroll
            for (int c = 0; c < 2; c++) {
                acc[r][c] = MFMA16(af[r][0], bfr[c][0], acc[r][c]);
                acc[r][c] = MFMA16(af[r][1], bfr[c][1], acc[r][c]);
            }
        __syncthreads();
    }

    #pragma unroll
    for (int r = 0; r < 4; r++) {
        const int mbase = m0 + wm * 64 + r * 16 + quad * 4;
        #pragma unroll
        for (int c = 0; c < 2; c++) {
            const int n = n0 + wn * 32 + c * 16 + lm;
            #pragma unroll
            for (int reg = 0; reg < 4; reg++) {
                const int m = mbase + reg;
                float v = acc[r][c][reg] + bias[n] + resf[(size_t)m * N + n];
                outb[(size_t)m * N + n] = f2b(v);
            }
        }
    }
}

// ---------------- Pass 1: Lr[s] = 1 / sum_{t>=s} exp(sc*q_t.k_s) ----------------
// 64-key strips, pairs {i,31-i} -> grid (32 bh, 16 pairs) = 512 blocks, 33 iters
// each. Waves 4(t)x2(s-half). K frags strip-resident in registers. LDS ~29KB.
__global__ __launch_bounds__(512) void colsum_mfma(const bf16* __restrict__ qkv,
                                                   float* __restrict__ Lr) {
    __shared__ short Ks[64 * 72];
    __shared__ short Qs[2][64 * 72];
    __shared__ float red[4][64];
    const int tid = threadIdx.x, lane = tid & 63, wv = tid >> 6;
    const int wq = wv >> 1, wk = wv & 1;
    const int lm = lane & 15, quad = lane >> 4;
    const int bh = blockIdx.x, bb = bh >> 3, hh = bh & 7;
    const bf16* qbase = qkv + (size_t)bb * T_ * 1024 + hh * 64;
    const bf16* kbase = qbase + 512;
    const int r_ = tid >> 3, ch = tid & 7;
    for (int half = 0; half < 2; half++) {
        const int strip = half ? 31 - (int)blockIdx.y : (int)blockIdx.y;
        const int s0 = strip * 64;
        *(s8v*)&Ks[r_ * 72 + ch * 8] =
            *(const s8v*)(kbase + (size_t)(s0 + r_) * 1024 + ch * 8);
        s8v qr = *(const s8v*)(qbase + (size_t)(s0 + r_) * 1024 + ch * 8);
        b8v bk[2][2];
        float csum[2] = {};
        const int niter = 32 - strip;
        for (int it = 0; it < niter; it++) {
            const int buf = it & 1;
            *(s8v*)&Qs[buf][r_ * 72 + ch * 8] = qr;
            __syncthreads();
            if (it == 0) {
                #pragma unroll
                for (int c = 0; c < 2; c++)
                    #pragma unroll
                    for (int k = 0; k < 2; k++)
                        bk[c][k] = *(const b8v*)&Ks[(wk * 32 + c * 16 + lm) * 72 +
                                                    k * 32 + quad * 8];
            }
            if (it + 1 < niter) {
                const int t1 = s0 + (it + 1) * 64;
                qr = *(const s8v*)(qbase + (size_t)(t1 + r_) * 1024 + ch * 8);
            }
            const int t0 = s0 + it * 64;
            b8v aq[2];
            #pragma unroll
            for (int k = 0; k < 2; k++)
                aq[k] = *(const b8v*)&Qs[buf][(wq * 16 + lm) * 72 + k * 32 + quad * 8];
            if (it == 0) {  // diagonal: causal mask needed
                #pragma unroll
                for (int c = 0; c < 2; c++) {
                    f32x4 S = {0.f, 0.f, 0.f, 0.f};
                    S = MFMA16(aq[0], bk[c][0], S);
                    S = MFMA16(aq[1], bk[c][1], S);
                    const int s = s0 + wk * 32 + c * 16 + lm;
                    #pragma unroll
                    for (int reg = 0; reg < 4; reg++) {
                        int t = t0 + wq * 16 + quad * 4 + reg;
                        if (t >= s) csum[c] += EXP2F(S[reg] * SCALE2_);
                    }
                }
            } else {  // strictly below diagonal: no mask
                #pragma unroll
                for (int c = 0; c < 2; c++) {
                    f32x4 S = {0.f, 0.f, 0.f, 0.f};
                    S = MFMA16(aq[0], bk[c][0], S);
                    S = MFMA16(aq[1], bk[c][1], S);
                    csum[c] += EXP2F(S[0] * SCALE2_) + EXP2F(S[1] * SCALE2_) +
                               EXP2F(S[2] * SCALE2_) + EXP2F(S[3] * SCALE2_);
                }
            }
        }
        __syncthreads();
        #pragma unroll
        for (int c = 0; c < 2; c++) {
            float v = csum[c];
            v += __shfl_xor(v, 16);
            v += __shfl_xor(v, 32);
            if (lane < 16) red[wq][wk * 32 + c * 16 + lane] = v;
        }
        __syncthreads();
        if (tid < 64) {
            float s = red[0][tid] + red[1][tid] + red[2][tid] + red[3][tid];
            Lr[(size_t)bh * T_ + s0 + tid] = 1.0f / s;
        }
        __syncthreads();
    }
}

// ---------------- Pass 2: out_t = sum_{s<=t} exp(sc*q_t.k_s) * (v_s * Lr_s) ----------------
// 128-query strips, pairs {p,15-p}; each block handles even OR odd 64-key tiles
// (parity) -> 512 blocks, 17 iters each. LDS arena 72KB (Ored aliased onto dead
// K/V dbuf) -> 2 blocks/CU. Partial O -> p0/p1, merged inside the Wo GEMM.
__global__ __launch_bounds__(512) void attnout_mfma(const bf16* __restrict__ qkv,
                                                    const bf16* __restrict__ vt,
                                                    const float* __restrict__ Lr,
                                                    bf16* __restrict__ pout0,
                                                    bf16* __restrict__ pout1) {
    __shared__ __align__(16) char arena[73728];
    short* const Qs = (short*)arena;                 // [128*72] 18432 B
    short* const Ps = (short*)(arena + 18432);       // [128*72] 18432 B
    short* const KV = (short*)(arena + 36864);       // Ks[2][64*72] Vt[2][64*72] 36864 B
    float* const Ored = (float*)(arena + 36864);     // [64*132] 33792 B (aliases KV)
    const int tid = threadIdx.x, lane = tid & 63, wv = tid >> 6;
    const int wm = wv >> 1, wn = wv & 1;
    const int lm = lane & 15, quad = lane >> 4;
    const int bh = blockIdx.x, bb = bh >> 3, hh = bh & 7;
    const int pairIdx = blockIdx.y >> 1, parity = blockIdx.y & 1;
    bf16* const outP = parity ? pout1 : pout0;
    const bf16* qbase = qkv + (size_t)bb * T_ * 1024 + hh * 64;
    const bf16* kbase = qbase + 512;
    const bf16* vtb = vt + ((size_t)bb * 512 + hh * 64) * T_;
    const float* Lrb = Lr + (size_t)bh * T_;
    const int r_ = tid >> 3, ch = tid & 7;
    for (int half = 0; half < 2; half++) {
        const int strip = half ? 15 - pairIdx : pairIdx;
        const int tb = strip * 128;
        #pragma unroll
        for (int cc = 0; cc < 2; cc++) {
            int idx = cc * 512 + tid, qr = idx >> 3, qc = idx & 7;
            *(s8v*)&Qs[qr * 72 + qc * 8] =
                *(const s8v*)(qbase + (size_t)(tb + qr) * 1024 + qc * 8);
        }
        int s0 = parity * 64;
        s8v kreg = *(const s8v*)(kbase + (size_t)(s0 + r_) * 1024 + ch * 8);
        s8v vreg = *(const s8v*)(vtb + (size_t)r_ * T_ + s0 + ch * 8);
        float4 lr0 = *(const float4*)(Lrb + s0 + ch * 8);
        float4 lr1 = *(const float4*)(Lrb + s0 + ch * 8 + 4);
        b8v bq[2][2];
        f32x4 o[2][4];
        #pragma unroll
        for (int r = 0; r < 2; r++)
            #pragma unroll
            for (int c = 0; c < 4; c++) {
                f32x4 z = {0.f, 0.f, 0.f, 0.f};
                o[r][c] = z;
            }
        const int niter = strip + 1;
        for (int it = 0; it < niter; it++) {
            s0 = (parity + 2 * it) * 64;
            const int buf = it & 1;
            short* const Ksb = KV + buf * (64 * 72);
            short* const Vsb = KV + 2 * (64 * 72) + buf * (64 * 72);
            uint4 vs;
            vs.x = pk2(s2f(vreg[0]) * lr0.x, s2f(vreg[1]) * lr0.y);
            vs.y = pk2(s2f(vreg[2]) * lr0.z, s2f(vreg[3]) * lr0.w);
            vs.z = pk2(s2f(vreg[4]) * lr1.x, s2f(vreg[5]) * lr1.y);
            vs.w = pk2(s2f(vreg[6]) * lr1.z, s2f(vreg[7]) * lr1.w);
            *(s8v*)&Ksb[r_ * 72 + ch * 8] = kreg;
            *(uint4*)&Vsb[r_ * 72 + ch * 8] = vs;
            __syncthreads();
            if (it == 0) {
                #pragma unroll
                for (int r = 0; r < 2; r++)
                    #pragma unroll
                    for (int k = 0; k < 2; k++)
                        bq[r][k] = *(const b8v*)&Qs[(wm * 32 + r * 16 + lm) * 72 +
                                                    k * 32 + quad * 8];
            }
            if (it + 1 < niter) {
                const int s1 = s0 + 128;
                kreg = *(const s8v*)(kbase + (size_t)(s1 + r_) * 1024 + ch * 8);
                vreg = *(const s8v*)(vtb + (size_t)r_ * T_ + s1 + ch * 8);
                lr0 = *(const float4*)(Lrb + s1 + ch * 8);
                lr1 = *(const float4*)(Lrb + s1 + ch * 8 + 4);
            }
            b8v ak[2][2];
            #pragma unroll
            for (int c = 0; c < 2; c++)
                #pragma unroll
                for (int k = 0; k < 2; k++)
                    ak[c][k] = *(const b8v*)&Ksb[(wn * 32 + c * 16 + lm) * 72 +
                                                 k * 32 + quad * 8];
            const bool masked = (it == niter - 1);
            #pragma unroll
            for (int r = 0; r < 2; r++) {
                const int t = tb + wm * 32 + r * 16 + lm;
                #pragma unroll
                for (int c = 0; c < 2; c++) {
                    f32x4 S = {0.f, 0.f, 0.f, 0.f};
                    S = MFMA16(ak[c][0], bq[r][0], S);
                    S = MFMA16(ak[c][1], bq[r][1], S);
                    float e[4];
                    #pragma unroll
                    for (int reg = 0; reg < 4; reg++)
                        e[reg] = EXP2F(S[reg] * SCALE2_);
                    if (masked) {
                        #pragma unroll
                        for (int reg = 0; reg < 4; reg++) {
                            int s = s0 + wn * 32 + c * 16 + quad * 4 + reg;
                            if (t < s) e[reg] = 0.f;
                        }
                    }
                    uint2 u;
                    u.x = pk2(e[0], e[1]);
                    u.y = pk2(e[2], e[3]);
                    *(uint2*)&Ps[(wm * 32 + r * 16 + lm) * 72 + wn * 32 + c * 16 +
                                 quad * 4] = u;
                }
            }
            #pragma unroll
            for (int r = 0; r < 2; r++) {
                b8v ap = *(const b8v*)&Ps[(wm * 32 + r * 16 + lm) * 72 + wn * 32 +
                                          quad * 8];
                #pragma unroll
                for (int c = 0; c < 4; c++) {
                    b8v bv = *(const b8v*)&Vsb[(c * 16 + lm) * 72 + wn * 32 + quad * 8];
                    o[r][c] = MFMA16(ap, bv, o[r][c]);
                }
            }
        }
        __syncthreads();
        if (wn == 1) {
            #pragma unroll
            for (int r = 0; r < 2; r++)
                #pragma unroll
                for (int c = 0; c < 4; c++)
                    *(f32x4*)&Ored[(c * 16 + lm) * 132 + wm * 32 + r * 16 + quad * 4] =
                        o[r][c];
        }
        __syncthreads();
        if (wn == 0) {
            #pragma unroll
            for (int r = 0; r < 2; r++)
                #pragma unroll
                for (int c = 0; c < 4; c++) {
                    f32x4 p = *(const f32x4*)&Ored[(c * 16 + lm) * 132 + wm * 32 +
                                                   r * 16 + quad * 4];
                    #pragma unroll
                    for (int reg = 0; reg < 4; reg++)
                        outP[(size_t)(bb * T_ + tb + wm * 32 + r * 16 + quad * 4 +
                                      reg) * C_ + hh * 64 + c * 16 + lm] =
                            f2b(o[r][c][reg] + p[reg]);
                }
        }
        __syncthreads();
    }
}

extern "C" void kernel_launch(void* const* d_in, const int* in_sizes, int n_in,
                              void* d_out, int out_size, void* d_ws, size_t ws_size,
                              hipStream_t stream) {
    const float* x   = (const float*)d_in[0];
    const float* Wq  = (const float*)d_in[1];
    const float* Wk  = (const float*)d_in[2];
    const float* Wv  = (const float*)d_in[3];
    const float* Wo  = (const float*)d_in[4];
    const float* bo  = (const float*)d_in[5];
    const float* W1  = (const float*)d_in[6];
    const float* b1  = (const float*)d_in[7];
    const float* W2  = (const float*)d_in[8];
    const float* b2  = (const float*)d_in[9];
    const float* g1  = (const float*)d_in[10];
    const float* be1 = (const float*)d_in[11];
    const float* g2  = (const float*)d_in[12];
    const float* be2 = (const float*)d_in[13];
    float* out = (float*)d_out;

    char* w = (char*)d_ws;
    auto alloc = [&](size_t bytes) -> void* {
        void* p = (void*)w;
        w += (bytes + 255) & ~(size_t)255;
        return p;
    };
    bf16* regionA = (bf16*)alloc((size_t)BT_ * 2048 * sizeof(bf16));  // 32MB
    bf16* qkvb = regionA;                                // [BT][1024] (q|k)
    bf16* hbuf = regionA + (size_t)BT_ * 1536;           // [BT][512] -> attn partial 0
    bf16* ff1  = regionA;                                // [BT][2048]
    bf16* x1     = (bf16*)alloc((size_t)BT_ * C_ * sizeof(bf16));
    bf16* h2     = (bf16*)alloc((size_t)BT_ * C_ * sizeof(bf16));    // attn p1 / W2 part0
    bf16* vt     = (bf16*)alloc((size_t)B_ * 512 * T_ * sizeof(bf16)); // W2 part1
    bf16* WqkvT  = (bf16*)alloc((size_t)1536 * C_ * sizeof(bf16));
    bf16* WoT    = (bf16*)alloc((size_t)C_ * C_ * sizeof(bf16));
    bf16* W1T    = (bf16*)alloc((size_t)C4_ * C_ * sizeof(bf16));
    bf16* W2T    = (bf16*)alloc((size_t)C_ * C4_ * sizeof(bf16));
    float* Lr    = (float*)alloc((size_t)B_ * H_ * T_ * sizeof(float));
    bf16* partK  = h2;  // h2(8MB)+vt(8MB) contiguous = 16MB bf16 partials

    // 0+1. weight transposes + LN1 in one launch
    prep_kernel<<<768 + BT_, 256, 0, stream>>>(Wq, Wk, Wv, Wo, W1, W2,
                                               WqkvT, WoT, W1T, W2T,
                                               x, g1, be1, hbuf);
    // 2. QKV GEMM: [8192,1536,512]; q,k -> qkvb, v -> vt (transposed, coalesced)
    mfma_gemm<4><<<dim3(BT_ / 128, 1536 / 128), 256, 0, stream>>>(
        hbuf, WqkvT, nullptr, nullptr, qkvb, vt, BT_, 1536, C_);
    // 3. column-sum reciprocals (XCD-swizzled, 512 blocks)
    colsum_mfma<<<dim3(B_ * H_, 16), 512, 0, stream>>>(qkvb, Lr);
    // 4. attention output partials (XCD-swizzled, 512 blocks = 2/CU)
    attnout_mfma<<<dim3(B_ * H_, 16), 512, 0, stream>>>(qkvb, vt, Lr, hbuf, h2);
    // 5. x1 = x + (p0+p1) @ Wo + bo   (reduce_attn fused into A-staging)
    mfma_gemm2f<<<dim3(BT_ / 128, C_ / 128), 512, 0, stream>>>(
        hbuf, h2, WoT, bo, x, x1, BT_, C_, C_);
    // 6. h2 = LN(x1)
    ln_kernel<bf16><<<BT_, 256, 0, stream>>>(x1, g2, be2, h2);
    // 7. ff1 = relu(h2 @ W1 + b1)
    mfma_gemm<1><<<dim3(BT_ / 128, C4_ / 128), 256, 0, stream>>>(
        h2, W1T, b1, ff1, nullptr, nullptr, BT_, C4_, C_);
    // 8a. W2 split-K: partials (512 blocks -> 2/CU)
    mfma_gemm_sk<<<dim3(BT_ / 128, C_ / 128, 2), 256, 0, stream>>>(
        ff1, W2T, partK, BT_, C_, C4_, C4_ / 2);
    // 8b. out = p0 + p1 + b2 + x1
    reduce_w2<<<(BT_ * C_) / (256 * 4), 256, 0, stream>>>(partK, b2, x1, out);
}